// Round 9
// baseline (591.533 us; speedup 1.0000x reference)
//
#include <hip/hip_runtime.h>
#include <hip/hip_bf16.h>
#include <cstdint>
#include <cstddef>

#define BB 4
#define SS 2048
#define DM 1024
#define INNER 2048
#define CHUNK 64
#define NCHK (SS / CHUNK)  // 32

typedef __attribute__((ext_vector_type(8))) __bf16 bf16x8;
typedef __attribute__((ext_vector_type(4))) float f32x4;
typedef __attribute__((ext_vector_type(8))) unsigned short ushort8;
typedef __attribute__((ext_vector_type(4))) unsigned short ushort4v;

#define GPTR(p) ((const __attribute__((address_space(1))) void*)(p))
#define LPTR(p) ((__attribute__((address_space(3))) void*)(p))
#define SB() __builtin_amdgcn_sched_barrier(0)

__device__ inline float b2f(unsigned short h) {
  union { unsigned u; float f; } v; v.u = ((unsigned)h) << 16; return v.f;
}
__device__ inline unsigned short f2b(float f) {
  unsigned u = __float_as_uint(f);
  u += 0x7fff + ((u >> 16) & 1);   // round-to-nearest-even
  return (unsigned short)(u >> 16);
}
__device__ inline unsigned pack2(float lo, float hi) {
  return (unsigned)f2b(lo) | ((unsigned)f2b(hi) << 16);
}
__device__ inline float sigmoidf_(float x) { return 1.0f / (1.0f + __expf(-x)); }
__device__ inline float tanhf_(float x) { return 2.0f / (1.0f + __expf(-2.0f * x)) - 1.0f; }

// ---------------------------------------------------------------------------
// Transpose + cast: src fp32 [R][C] -> dst bf16 [C][R]
// ---------------------------------------------------------------------------
__global__ void transpose_cast_kernel(const float* __restrict__ src,
                                      unsigned short* __restrict__ dst,
                                      int R, int C) {
  __shared__ float tile[32][33];
  const int c0 = blockIdx.x * 32, r0 = blockIdx.y * 32;
  const int tx = threadIdx.x, ty = threadIdx.y;  // (32,8)
  #pragma unroll
  for (int j = ty; j < 32; j += 8)
    tile[j][tx] = src[(size_t)(r0 + j) * C + c0 + tx];
  __syncthreads();
  #pragma unroll
  for (int j = ty; j < 32; j += 8)
    dst[(size_t)(c0 + j) * R + r0 + tx] = f2b(tile[tx][j]);
}

// ---------------------------------------------------------------------------
// LayerNorm: x fp32 [8192][1024] -> xn bf16
// ---------------------------------------------------------------------------
__global__ __launch_bounds__(256) void layernorm_kernel(
    const float* __restrict__ x, const float* __restrict__ gamma,
    const float* __restrict__ beta, unsigned short* __restrict__ out) {
  const int row = blockIdx.x;
  const int tid = threadIdx.x;
  const float4 v = *(const float4*)(x + (size_t)row * DM + tid * 4);
  float s = v.x + v.y + v.z + v.w;
  #pragma unroll
  for (int o = 32; o >= 1; o >>= 1) s += __shfl_down(s, o, 64);
  __shared__ float red[8];
  const int wid = tid >> 6, lane = tid & 63;
  if (lane == 0) red[wid] = s;
  __syncthreads();
  const float mu = (red[0] + red[1] + red[2] + red[3]) * (1.f / DM);
  const float d0 = v.x - mu, d1 = v.y - mu, d2 = v.z - mu, d3 = v.w - mu;
  float sq = d0 * d0 + d1 * d1 + d2 * d2 + d3 * d3;
  #pragma unroll
  for (int o = 32; o >= 1; o >>= 1) sq += __shfl_down(sq, o, 64);
  if (lane == 0) red[4 + wid] = sq;
  __syncthreads();
  const float var = (red[4] + red[5] + red[6] + red[7]) * (1.f / DM);
  const float rs = rsqrtf(var + 1e-5f);
  const int c0 = tid * 4;
  ushort4v o4;
  o4[0] = f2b(d0 * rs * gamma[c0 + 0] + beta[c0 + 0]);
  o4[1] = f2b(d1 * rs * gamma[c0 + 1] + beta[c0 + 1]);
  o4[2] = f2b(d2 * rs * gamma[c0 + 2] + beta[c0 + 2]);
  o4[3] = f2b(d3 * rs * gamma[c0 + 3] + beta[c0 + 3]);
  *(ushort4v*)(out + (size_t)row * DM + c0) = o4;
}

// ---------------------------------------------------------------------------
// 256x128 GEMM, BK=32, 512 threads (8 waves, 4Mx2N, wave tile 64x64).
// 2 blocks/CU (48 KB LDS, <=128 regs/wave via __launch_bounds__(512,4)) +
// counted-vmcnt schedule (never drains in loop):
//   P1: stage A(t+1) | vmcnt(2)+bar | 6 ds_reads | 8 MFMA | bar
//   P2: stage B(t+1) |               2 ds_reads  | 8 MFMA | bar
// vmcnt ledger at P1: outstanding = [A(t)2, B(t)1, A(t+1)2]; vmcnt(2) drains
// A(t),B(t) -> tile t resident, A(t+1) stays in flight.
// WAR: stage(buf[x]) is program-ordered after the barrier closing the last
// phase that read buf[x].
// LDS layout (16B units): u = (row>>4)*64 + slot*16 + (row&15)
//   -> per 16-row block = 64 units = 512 ELEMS (BK=32!). Fragment base:
//      a_off = wr*4*512 + l*8 (+mf*512); b_off = 8192 + wc*4*512 + l*8 (+nf*512)
//   -> ds_read_b128 lane-linear (conflict-free); staging: linear LDS dest,
//      per-lane permuted GLOBAL source.  [R7 bug was mf*1024 stride here.]
// Operand-swapped MFMA: acc = mfma(B, A, acc) -> lane holds 4 consecutive C
// columns -> packed stores.
// OUTMODE 0: bf16. OUTMODE 1: fp32 + residual. OUTMODE 2: abc-fused
// (seg0/1 sigmoid, seg2 tanh; segments contiguous [M][2048] bf16 blocks).
// ---------------------------------------------------------------------------
template <int OUTMODE>
__global__ __launch_bounds__(512, 4) void gemm_mn(
    const unsigned short* __restrict__ A, const unsigned short* __restrict__ Bt,
    const float* __restrict__ bias, void* __restrict__ Cout,
    const float* __restrict__ resid, int M, int N, int K, int nbx) {
  __shared__ unsigned short lds[2 * 12288];  // 48 KB: 2 bufs x (A 16KB + B 8KB)
  const int tid = threadIdx.x;
  // bijective XCD swizzle (gridDim.x % 8 == 0)
  const int nwg = gridDim.x;
  const int cpx = nwg >> 3;
  const int bid = blockIdx.x;
  const int swz = (bid & 7) * cpx + (bid >> 3);
  const int m0 = (swz / nbx) * 256, n0 = (swz % nbx) * 128;

  const int l = tid & 63, w = tid >> 6;
  const int wr = w >> 1, wc = w & 1;          // 4(M) x 2(N) wave grid
  const int NT = K >> 5;                      // K-tiles of 32

  // fragment bases (elems): lane-linear reads; frag stride 512
  const int a_off = (wr * 4) * 512 + l * 8;          // + mf*512
  const int b_off = 8192 + (wc * 4) * 512 + l * 8;   // + nf*512

  f32x4 acc[4][4];
  #pragma unroll
  for (int i = 0; i < 4; i++)
    #pragma unroll
    for (int j = 0; j < 4; j++) acc[i][j] = (f32x4){0.f, 0.f, 0.f, 0.f};

  // staging source addresses (fixed per thread; only k0 varies)
  const int q0 = tid, q1 = tid + 512;
  const int row0 = ((q0 >> 6) << 4) | (q0 & 15), slot0 = (q0 >> 4) & 3;
  const int row1 = ((q1 >> 6) << 4) | (q1 & 15), slot1 = (q1 >> 4) & 3;
  const unsigned short* Ap0 = A + (size_t)(m0 + row0) * K + slot0 * 8;
  const unsigned short* Ap1 = A + (size_t)(m0 + row1) * K + slot1 * 8;
  const unsigned short* Bp0 = Bt + (size_t)(n0 + row0) * K + slot0 * 8;

  auto stageA = [&](int kt) {
    int ktw = kt; if (ktw >= NT) ktw -= NT;
    const int k0 = ktw << 5;
    const int bo = (kt & 1) * 12288;
    __builtin_amdgcn_global_load_lds(GPTR(Ap0 + k0), LPTR(&lds[bo + q0 * 8]), 16, 0, 0);
    __builtin_amdgcn_global_load_lds(GPTR(Ap1 + k0), LPTR(&lds[bo + q1 * 8]), 16, 0, 0);
  };
  auto stageB = [&](int kt) {
    int ktw = kt; if (ktw >= NT) ktw -= NT;
    const int k0 = ktw << 5;
    const int bo = (kt & 1) * 12288 + 8192;
    __builtin_amdgcn_global_load_lds(GPTR(Bp0 + k0), LPTR(&lds[bo + tid * 8]), 16, 0, 0);
  };

  // prologue: tile 0 fully staged (3 loads/thread outstanding)
  stageA(0); stageB(0);

  for (int t = 0; t < NT; t++) {
    const int tbo = (t & 1) * 12288;
    bf16x8 af[4], bfv[4];

    // ===== P1: stage A(t+1); tile t resident; mf 0-1 =====
    stageA(t + 1);
    SB();
    asm volatile("s_waitcnt vmcnt(2)" ::: "memory");
    SB();
    __builtin_amdgcn_s_barrier();
    SB();
    #pragma unroll
    for (int nf = 0; nf < 4; nf++)
      bfv[nf] = *(const bf16x8*)&lds[tbo + b_off + nf * 512];
    af[0] = *(const bf16x8*)&lds[tbo + a_off + 0 * 512];
    af[1] = *(const bf16x8*)&lds[tbo + a_off + 1 * 512];
    asm volatile("s_waitcnt lgkmcnt(0)" ::: "memory");
    SB();
    __builtin_amdgcn_s_setprio(1);
    #pragma unroll
    for (int mf = 0; mf < 2; mf++)
      #pragma unroll
      for (int nf = 0; nf < 4; nf++)
        acc[mf][nf] = __builtin_amdgcn_mfma_f32_16x16x32_bf16(bfv[nf], af[mf], acc[mf][nf], 0, 0, 0);
    __builtin_amdgcn_s_setprio(0);
    SB();
    __builtin_amdgcn_s_barrier();
    SB();

    // ===== P2: stage B(t+1); mf 2-3 =====
    stageB(t + 1);
    SB();
    af[2] = *(const bf16x8*)&lds[tbo + a_off + 2 * 512];
    af[3] = *(const bf16x8*)&lds[tbo + a_off + 3 * 512];
    asm volatile("s_waitcnt lgkmcnt(0)" ::: "memory");
    SB();
    __builtin_amdgcn_s_setprio(1);
    #pragma unroll
    for (int mf = 2; mf < 4; mf++)
      #pragma unroll
      for (int nf = 0; nf < 4; nf++)
        acc[mf][nf] = __builtin_amdgcn_mfma_f32_16x16x32_bf16(bfv[nf], af[mf], acc[mf][nf], 0, 0, 0);
    __builtin_amdgcn_s_setprio(0);
    SB();
    __builtin_amdgcn_s_barrier();
    SB();
  }
  // drain stray prefetches before epilogue / endpgm
  asm volatile("s_waitcnt vmcnt(0)" ::: "memory");

  // epilogue: lane holds C[row][colb..colb+3]
  const int rowl = m0 + wr * 64 + (l & 15);
  const int coll = n0 + wc * 64 + (l >> 4) * 4;
  const int seg = (OUTMODE == 2) ? (n0 >> 11) : 0;
  unsigned short* outseg = (unsigned short*)Cout +
      (OUTMODE == 2 ? (size_t)seg * M * 2048 : 0);
  #pragma unroll
  for (int mf = 0; mf < 4; mf++) {
    const int row = rowl + mf * 16;
    #pragma unroll
    for (int nf = 0; nf < 4; nf++) {
      const int colb = coll + nf * 16;
      const float4 bv = *(const float4*)(bias + colb);
      float v0 = acc[mf][nf][0] + bv.x;
      float v1 = acc[mf][nf][1] + bv.y;
      float v2 = acc[mf][nf][2] + bv.z;
      float v3 = acc[mf][nf][3] + bv.w;
      if (OUTMODE == 2) {
        if (seg == 2) {
          v0 = tanhf_(v0); v1 = tanhf_(v1); v2 = tanhf_(v2); v3 = tanhf_(v3);
        } else {
          v0 = sigmoidf_(v0); v1 = sigmoidf_(v1); v2 = sigmoidf_(v2); v3 = sigmoidf_(v3);
        }
        uint2 pk = {pack2(v0, v1), pack2(v2, v3)};
        *(uint2*)(outseg + (size_t)row * 2048 + (colb & 2047)) = pk;
      } else if (OUTMODE == 1) {
        const size_t idx = (size_t)row * N + colb;
        const float4 rv = *(const float4*)(resid + idx);
        float4 ov = {v0 + rv.x, v1 + rv.y, v2 + rv.z, v3 + rv.w};
        *(float4*)((float*)Cout + idx) = ov;
      } else {
        uint2 pk = {pack2(v0, v1), pack2(v2, v3)};
        *(uint2*)((unsigned short*)Cout + (size_t)row * N + colb) = pk;
      }
    }
  }
}

// ---------------------------------------------------------------------------
// Causal depthwise conv (K=3) + SiLU + gate.  proj bf16 [B*S][2*INNER].
// ---------------------------------------------------------------------------
__global__ __launch_bounds__(256) void conv_gate_kernel(
    const unsigned short* __restrict__ proj, const float* __restrict__ conv_w,
    const float* __restrict__ conv_b, unsigned short* __restrict__ u) {
  const size_t idx = ((size_t)blockIdx.x * 256 + threadIdx.x) * 8;
  const int d = (int)(idx & (INNER - 1));
  const size_t bt = idx >> 11;
  const int t = (int)(bt & (SS - 1));
  const size_t rowbase = bt * (2 * INNER);
  const ushort8 zero = {0, 0, 0, 0, 0, 0, 0, 0};
  ushort8 p0 = *(const ushort8*)(proj + rowbase + d);
  ushort8 p1 = zero, p2 = zero;
  if (t >= 1) p1 = *(const ushort8*)(proj + rowbase - 2 * INNER + d);
  if (t >= 2) p2 = *(const ushort8*)(proj + rowbase - 4 * INNER + d);
  ushort8 g = *(const ushort8*)(proj + rowbase + INNER + d);
  ushort8 res;
  #pragma unroll
  for (int j = 0; j < 8; j++) {
    const int dj = d + j;
    float sv = conv_b[dj] + conv_w[dj * 3] * b2f(p2[j]) +
               conv_w[dj * 3 + 1] * b2f(p1[j]) + conv_w[dj * 3 + 2] * b2f(p0[j]);
    float uu = sv * sigmoidf_(sv) * sigmoidf_(b2f(g[j]));
    res[j] = f2b(uu);
  }
  *(ushort8*)(u + idx) = res;
}

// ---------------------------------------------------------------------------
// Chunked parallel scan, 3 phases.
// ---------------------------------------------------------------------------
__global__ __launch_bounds__(256) void scan_phase1(
    const unsigned short* __restrict__ a, const unsigned short* __restrict__ b,
    const unsigned short* __restrict__ u,
    float* __restrict__ P, float* __restrict__ S) {
  const int g = blockIdx.x * 256 + threadIdx.x;   // 65536 threads
  const int ch = (g & (INNER / 4 - 1)) * 4;
  const int chunk = (g >> 9) & (NCHK - 1);
  const int bb = g >> 14;
  size_t base = ((size_t)bb * SS + (size_t)chunk * CHUNK) * INNER + ch;
  float st0 = 0.f, st1 = 0.f, st2 = 0.f, st3 = 0.f;
  float p0 = 1.f, p1 = 1.f, p2 = 1.f, p3 = 1.f;
  for (int t = 0; t < CHUNK; t++) {
    const ushort4v av = *(const ushort4v*)(a + base);
    const ushort4v bv = *(const ushort4v*)(b + base);
    const ushort4v uv = *(const ushort4v*)(u + base);
    const float a0 = b2f(av[0]), a1 = b2f(av[1]), a2 = b2f(av[2]), a3 = b2f(av[3]);
    st0 = fmaf(a0, st0, b2f(bv[0]) * b2f(uv[0])); p0 *= a0;
    st1 = fmaf(a1, st1, b2f(bv[1]) * b2f(uv[1])); p1 *= a1;
    st2 = fmaf(a2, st2, b2f(bv[2]) * b2f(uv[2])); p2 *= a2;
    st3 = fmaf(a3, st3, b2f(bv[3]) * b2f(uv[3])); p3 *= a3;
    base += INNER;
  }
  const size_t o = ((size_t)bb * NCHK + chunk) * INNER + ch;
  *(float4*)(P + o) = (float4){p0, p1, p2, p3};
  *(float4*)(S + o) = (float4){st0, st1, st2, st3};
}

__global__ __launch_bounds__(256) void scan_phase2(
    const float* __restrict__ P, const float* __restrict__ S,
    float* __restrict__ Carry) {
  const int g = blockIdx.x * 256 + threadIdx.x;   // 8192 threads
  const int ch = g & (INNER - 1);
  const int bb = g >> 11;
  float carry = 0.f;
  for (int k = 0; k < NCHK; k++) {
    const size_t o = ((size_t)bb * NCHK + k) * INNER + ch;
    Carry[o] = carry;
    carry = fmaf(P[o], carry, S[o]);
  }
}

__global__ __launch_bounds__(256) void scan_phase3(
    const unsigned short* __restrict__ a, const unsigned short* __restrict__ b,
    const unsigned short* __restrict__ c, unsigned short* __restrict__ u,
    const float* __restrict__ Carry) {
  const int g = blockIdx.x * 256 + threadIdx.x;   // 65536 threads
  const int ch = (g & (INNER / 4 - 1)) * 4;
  const int chunk = (g >> 9) & (NCHK - 1);
  const int bb = g >> 14;
  size_t base = ((size_t)bb * SS + (size_t)chunk * CHUNK) * INNER + ch;
  const size_t o = ((size_t)bb * NCHK + chunk) * INNER + ch;
  const float4 cv = *(const float4*)(Carry + o);
  float st0 = cv.x, st1 = cv.y, st2 = cv.z, st3 = cv.w;
  for (int t = 0; t < CHUNK; t++) {
    const ushort4v av = *(const ushort4v*)(a + base);
    const ushort4v bv = *(const ushort4v*)(b + base);
    const ushort4v ccv = *(const ushort4v*)(c + base);
    const ushort4v uv = *(const ushort4v*)(u + base);
    const float u0 = b2f(uv[0]), u1 = b2f(uv[1]), u2 = b2f(uv[2]), u3 = b2f(uv[3]);
    st0 = fmaf(b2f(av[0]), st0, b2f(bv[0]) * u0);
    st1 = fmaf(b2f(av[1]), st1, b2f(bv[1]) * u1);
    st2 = fmaf(b2f(av[2]), st2, b2f(bv[2]) * u2);
    st3 = fmaf(b2f(av[3]), st3, b2f(bv[3]) * u3);
    ushort4v yv;
    yv[0] = f2b(fmaf(b2f(ccv[0]), st0, u0));
    yv[1] = f2b(fmaf(b2f(ccv[1]), st1, u1));
    yv[2] = f2b(fmaf(b2f(ccv[2]), st2, u2));
    yv[3] = f2b(fmaf(b2f(ccv[3]), st3, u3));
    *(ushort4v*)(u + base) = yv;
    base += INNER;
  }
}

// ---------------------------------------------------------------------------
extern "C" void kernel_launch(void* const* d_in, const int* in_sizes, int n_in,
                              void* d_out, int out_size, void* d_ws, size_t ws_size,
                              hipStream_t stream) {
  const float* x      = (const float*)d_in[0];
  const float* W_in   = (const float*)d_in[1];
  const float* b_in   = (const float*)d_in[2];
  const float* conv_w = (const float*)d_in[3];
  const float* conv_b = (const float*)d_in[4];
  const float* Wa     = (const float*)d_in[5];
  const float* ba     = (const float*)d_in[6];
  const float* Wb     = (const float*)d_in[7];
  const float* b_b    = (const float*)d_in[8];
  const float* Wc     = (const float*)d_in[9];
  const float* bc     = (const float*)d_in[10];
  const float* Wo     = (const float*)d_in[11];
  const float* bo     = (const float*)d_in[12];
  const float* gamma  = (const float*)d_in[13];
  const float* beta   = (const float*)d_in[14];
  float* out = (float*)d_out;

  const size_t M = (size_t)BB * SS;  // 8192
  char* ws = (char*)d_ws;
  size_t off = 0;
  auto alloc = [&](size_t bytes) {
    char* p = ws + off;
    off += (bytes + 255) & ~(size_t)255;
    return p;
  };
  unsigned short* WinT  = (unsigned short*)alloc((size_t)4096 * 1024 * 2);  // 8 MB
  unsigned short* WabcT = (unsigned short*)alloc((size_t)6144 * 2048 * 2);  // 24 MB
  unsigned short* WoT   = (unsigned short*)alloc((size_t)1024 * 2048 * 2);  // 4 MB
  float*          biasABC = (float*)alloc(6144 * 4);
  unsigned short* xnB   = (unsigned short*)alloc(M * DM * 2);               // 16 MB
  unsigned short* uB    = (unsigned short*)alloc(M * INNER * 2);            // 32 MB
  unsigned short* abc   = (unsigned short*)alloc(3 * M * INNER * 2);        // 96 MB
  unsigned short* proj = abc;
  unsigned short* aB = abc;
  unsigned short* bB = abc + M * INNER;
  unsigned short* cB = abc + 2 * M * INNER;
  float* Pbuf  = (float*)xnB;          // xnB dead after proj GEMM
  float* Sbuf  = Pbuf + (size_t)BB * NCHK * INNER;
  float* Carry = Sbuf + (size_t)BB * NCHK * INNER;

  hipMemcpyAsync(biasABC,        ba,  2048 * 4, hipMemcpyDeviceToDevice, stream);
  hipMemcpyAsync(biasABC + 2048, b_b, 2048 * 4, hipMemcpyDeviceToDevice, stream);
  hipMemcpyAsync(biasABC + 4096, bc,  2048 * 4, hipMemcpyDeviceToDevice, stream);

  const dim3 tb(32, 8);
  transpose_cast_kernel<<<dim3(128, 32), tb, 0, stream>>>(W_in, WinT, 1024, 4096);
  transpose_cast_kernel<<<dim3(64, 64), tb, 0, stream>>>(Wa, WabcT, 2048, 2048);
  transpose_cast_kernel<<<dim3(64, 64), tb, 0, stream>>>(Wb, WabcT + 2048 * 2048, 2048, 2048);
  transpose_cast_kernel<<<dim3(64, 64), tb, 0, stream>>>(Wc, WabcT + 2 * 2048 * 2048, 2048, 2048);
  transpose_cast_kernel<<<dim3(32, 64), tb, 0, stream>>>(Wo, WoT, 2048, 1024);

  layernorm_kernel<<<M, 256, 0, stream>>>(x, gamma, beta, xnB);

  // proj = xn @ W_in + b_in            [8192 x 4096], grid 32x32 = 1024
  gemm_mn<0><<<dim3(1024), 512, 0, stream>>>(
      xnB, WinT, b_in, proj, nullptr, M, 4096, 1024, 32);

  // u = silu(conv(projected)) * sigmoid(gate)
  conv_gate_kernel<<<(M * INNER) / (256 * 8), 256, 0, stream>>>(proj, conv_w, conv_b, uB);

  // a,b,c fused: [8192 x 6144], grid 32x48 = 1536
  gemm_mn<2><<<dim3(1536), 512, 0, stream>>>(
      uB, WabcT, biasABC, abc, nullptr, M, 6144, 2048, 48);

  // chunked scan (y overwrites u)
  scan_phase1<<<256, 256, 0, stream>>>(aB, bB, uB, Pbuf, Sbuf);
  scan_phase2<<<32, 256, 0, stream>>>(Pbuf, Sbuf, Carry);
  scan_phase3<<<256, 256, 0, stream>>>(aB, bB, cB, uB, Carry);

  // out = x + y @ Wo + bo              [8192 x 1024] fp32, grid 32x8 = 256
  gemm_mn<1><<<dim3(256), 512, 0, stream>>>(
      uB, WoT, bo, out, x, M, 1024, 2048, 8);
}

// Round 10
// 524.371 us; speedup vs baseline: 1.1281x; 1.1281x over previous
//
#include <hip/hip_runtime.h>
#include <hip/hip_bf16.h>
#include <cstdint>
#include <cstddef>

#define BB 4
#define SS 2048
#define DM 1024
#define INNER 2048
#define CHUNK 64
#define NCHK (SS / CHUNK)  // 32

typedef __attribute__((ext_vector_type(8))) __bf16 bf16x8;
typedef __attribute__((ext_vector_type(4))) float f32x4;
typedef __attribute__((ext_vector_type(8))) unsigned short ushort8;
typedef __attribute__((ext_vector_type(4))) unsigned short ushort4v;

#define GPTR(p) ((const __attribute__((address_space(1))) void*)(p))
#define LPTR(p) ((__attribute__((address_space(3))) void*)(p))
#define SB() __builtin_amdgcn_sched_barrier(0)

__device__ inline float b2f(unsigned short h) {
  union { unsigned u; float f; } v; v.u = ((unsigned)h) << 16; return v.f;
}
__device__ inline unsigned short f2b(float f) {
  unsigned u = __float_as_uint(f);
  u += 0x7fff + ((u >> 16) & 1);   // round-to-nearest-even
  return (unsigned short)(u >> 16);
}
__device__ inline unsigned pack2(float lo, float hi) {
  return (unsigned)f2b(lo) | ((unsigned)f2b(hi) << 16);
}
__device__ inline float sigmoidf_(float x) { return 1.0f / (1.0f + __expf(-x)); }
__device__ inline float tanhf_(float x) { return 2.0f / (1.0f + __expf(-2.0f * x)) - 1.0f; }

// ---------------------------------------------------------------------------
// Transpose + cast: src fp32 [R][C] -> dst bf16 [C][R]
// ---------------------------------------------------------------------------
__global__ void transpose_cast_kernel(const float* __restrict__ src,
                                      unsigned short* __restrict__ dst,
                                      int R, int C) {
  __shared__ float tile[32][33];
  const int c0 = blockIdx.x * 32, r0 = blockIdx.y * 32;
  const int tx = threadIdx.x, ty = threadIdx.y;  // (32,8)
  #pragma unroll
  for (int j = ty; j < 32; j += 8)
    tile[j][tx] = src[(size_t)(r0 + j) * C + c0 + tx];
  __syncthreads();
  #pragma unroll
  for (int j = ty; j < 32; j += 8)
    dst[(size_t)(c0 + j) * R + r0 + tx] = f2b(tile[tx][j]);
}

// ---------------------------------------------------------------------------
// LayerNorm: x fp32 [8192][1024] -> xn bf16
// ---------------------------------------------------------------------------
__global__ __launch_bounds__(256) void layernorm_kernel(
    const float* __restrict__ x, const float* __restrict__ gamma,
    const float* __restrict__ beta, unsigned short* __restrict__ out) {
  const int row = blockIdx.x;
  const int tid = threadIdx.x;
  const float4 v = *(const float4*)(x + (size_t)row * DM + tid * 4);
  float s = v.x + v.y + v.z + v.w;
  #pragma unroll
  for (int o = 32; o >= 1; o >>= 1) s += __shfl_down(s, o, 64);
  __shared__ float red[8];
  const int wid = tid >> 6, lane = tid & 63;
  if (lane == 0) red[wid] = s;
  __syncthreads();
  const float mu = (red[0] + red[1] + red[2] + red[3]) * (1.f / DM);
  const float d0 = v.x - mu, d1 = v.y - mu, d2 = v.z - mu, d3 = v.w - mu;
  float sq = d0 * d0 + d1 * d1 + d2 * d2 + d3 * d3;
  #pragma unroll
  for (int o = 32; o >= 1; o >>= 1) sq += __shfl_down(sq, o, 64);
  if (lane == 0) red[4 + wid] = sq;
  __syncthreads();
  const float var = (red[4] + red[5] + red[6] + red[7]) * (1.f / DM);
  const float rs = rsqrtf(var + 1e-5f);
  const int c0 = tid * 4;
  ushort4v o4;
  o4[0] = f2b(d0 * rs * gamma[c0 + 0] + beta[c0 + 0]);
  o4[1] = f2b(d1 * rs * gamma[c0 + 1] + beta[c0 + 1]);
  o4[2] = f2b(d2 * rs * gamma[c0 + 2] + beta[c0 + 2]);
  o4[3] = f2b(d3 * rs * gamma[c0 + 3] + beta[c0 + 3]);
  *(ushort4v*)(out + (size_t)row * DM + c0) = o4;
}

// ---------------------------------------------------------------------------
// 256x256 GEMM, BK=64, 512 threads (8 waves, 2Mx4N, wave tile 128x64).
// Software-pipelined LDS reads (one phase ahead, compiler-counted lgkmcnt):
//   boundary: stageA(t+1) | vmcnt(4) | bar | R1(8 reads)
//   P1: R2(4 reads) | MFMA1(16)      [compiler waits only R1]
//   P2: stageB(t+1) | R3(8) | MFMA2  [waits R2]
//   P3: R4(4) | MFMA3                [waits R3]
//   P4: MFMA4 | bar                  [waits R4 = full drain]
// -> DS pipe services next phase's reads while matrix pipe runs current MFMAs.
// 2 barriers per K-tile; vmcnt(4) never drains in loop.
// LDS layout (R6-verified, elems): A: wr*8192 + mf*1024 + kk*512 +
//   (l>>4)*128 + (l&15)*8; B region at +16384, same form with wc*4096/nf.
//   ds_read_b128 lane-linear (conflict-free); staging: linear LDS dest,
//   per-lane permuted GLOBAL source.
// Operand-swapped MFMA: acc = mfma(B, A, acc) -> lane holds 4 consecutive C
// columns -> packed stores.
// OUTMODE 0: bf16. OUTMODE 2: abc-fused (seg0/1 sigmoid, seg2 tanh).
// ---------------------------------------------------------------------------
template <int OUTMODE>
__global__ __launch_bounds__(512, 1) void gemm64(
    const unsigned short* __restrict__ A, const unsigned short* __restrict__ Bt,
    const float* __restrict__ bias, void* __restrict__ Cout,
    int M, int N, int K, int nbx) {
  __shared__ unsigned short lds[2 * 32768];  // 128 KB
  const int tid = threadIdx.x;
  // bijective XCD swizzle (gridDim.x % 8 == 0)
  const int nwg = gridDim.x;
  const int cpx = nwg >> 3;
  const int bid = blockIdx.x;
  const int swz = (bid & 7) * cpx + (bid >> 3);
  const int m0 = (swz / nbx) * 256, n0 = (swz % nbx) * 256;

  const int l = tid & 63, w = tid >> 6;
  const int wr = w >> 2, wc = w & 3;          // 2(M) x 4(N) wave grid
  const int NT = K >> 6;                      // K-tiles of 64

  // fragment base offsets (elems), kk adds 512, mf/nf add 1024
  const int a_off = (wr * 8) * 1024 + (l >> 4) * 128 + (l & 15) * 8;
  const int b_off = 16384 + (wc * 4) * 1024 + (l >> 4) * 128 + (l & 15) * 8;

  f32x4 acc[8][4];
  #pragma unroll
  for (int i = 0; i < 8; i++)
    #pragma unroll
    for (int j = 0; j < 4; j++) acc[i][j] = (f32x4){0.f, 0.f, 0.f, 0.f};

  // staging: unit u (16B) holds row=((u>>7)<<4)|(u&15), kslot=(u>>4)&7.
  const int r0 = ((tid >> 7) << 4) | (tid & 15);
  const int s0 = (tid >> 4) & 7;
  const unsigned short* Abase = A + (size_t)(m0 + r0) * K + s0 * 8;
  const unsigned short* Bbase = Bt + (size_t)(n0 + r0) * K + s0 * 8;
  const size_t rs64 = (size_t)64 * K;

  auto stageA = [&](int kt, int h) {
    int ktw = kt; if (ktw >= NT) ktw -= NT;
    const int k0 = ktw << 6;
    const int bo = (kt & 1) * 32768 + h * 8192 + tid * 8;
    const unsigned short* src = Abase + (size_t)(h * 128) * K + k0;
    __builtin_amdgcn_global_load_lds(GPTR(src), LPTR(&lds[bo]), 16, 0, 0);
    __builtin_amdgcn_global_load_lds(GPTR(src + rs64), LPTR(&lds[bo + 4096]), 16, 0, 0);
  };
  auto stageB = [&](int kt, int h) {
    int ktw = kt; if (ktw >= NT) ktw -= NT;
    const int k0 = ktw << 6;
    const int bo = (kt & 1) * 32768 + 16384 + h * 8192 + tid * 8;
    const unsigned short* src = Bbase + (size_t)(h * 128) * K + k0;
    __builtin_amdgcn_global_load_lds(GPTR(src), LPTR(&lds[bo]), 16, 0, 0);
    __builtin_amdgcn_global_load_lds(GPTR(src + rs64), LPTR(&lds[bo + 4096]), 16, 0, 0);
  };

  // prologue: tile 0 fully staged (8 loads outstanding)
  stageA(0, 0); stageA(0, 1); stageB(0, 0); stageB(0, 1);

  for (int t = 0; t < NT; t++) {
    const int tbo = (t & 1) * 32768;
    bf16x8 bfA[4], afA[4], afB[4], bfB[4], afC[4], afD[4];

    // ===== boundary: stage A(t+1); tile t resident =====
    stageA(t + 1, 0); stageA(t + 1, 1);
    SB();
    asm volatile("s_waitcnt vmcnt(4)" ::: "memory");
    SB();
    __builtin_amdgcn_s_barrier();
    SB();
    // R1: kk0 -> bfA (nf0-3), afA (mf0-3)
    #pragma unroll
    for (int nf = 0; nf < 4; nf++)
      bfA[nf] = *(const bf16x8*)&lds[tbo + b_off + nf * 1024];
    #pragma unroll
    for (int mf = 0; mf < 4; mf++)
      afA[mf] = *(const bf16x8*)&lds[tbo + a_off + mf * 1024];
    SB();
    // R2 (prefetch): kk0 -> afB (mf4-7)
    #pragma unroll
    for (int mf = 0; mf < 4; mf++)
      afB[mf] = *(const bf16x8*)&lds[tbo + a_off + (4 + mf) * 1024];
    SB();
    // MFMA1: mf0-3 x nf0-3, kk0   (compiler waits R1 only)
    __builtin_amdgcn_s_setprio(1);
    #pragma unroll
    for (int mf = 0; mf < 4; mf++)
      #pragma unroll
      for (int nf = 0; nf < 4; nf++)
        acc[mf][nf] = __builtin_amdgcn_mfma_f32_16x16x32_bf16(bfA[nf], afA[mf], acc[mf][nf], 0, 0, 0);
    __builtin_amdgcn_s_setprio(0);
    SB();
    // stage B(t+1)
    stageB(t + 1, 0); stageB(t + 1, 1);
    SB();
    // R3 (prefetch): kk1 -> bfB (nf0-3), afC (mf0-3)
    #pragma unroll
    for (int nf = 0; nf < 4; nf++)
      bfB[nf] = *(const bf16x8*)&lds[tbo + b_off + nf * 1024 + 512];
    #pragma unroll
    for (int mf = 0; mf < 4; mf++)
      afC[mf] = *(const bf16x8*)&lds[tbo + a_off + mf * 1024 + 512];
    SB();
    // MFMA2: mf4-7 x nf0-3, kk0   (waits R2)
    __builtin_amdgcn_s_setprio(1);
    #pragma unroll
    for (int mf = 0; mf < 4; mf++)
      #pragma unroll
      for (int nf = 0; nf < 4; nf++)
        acc[4 + mf][nf] = __builtin_amdgcn_mfma_f32_16x16x32_bf16(bfA[nf], afB[mf], acc[4 + mf][nf], 0, 0, 0);
    __builtin_amdgcn_s_setprio(0);
    SB();
    // R4 (prefetch): kk1 -> afD (mf4-7)
    #pragma unroll
    for (int mf = 0; mf < 4; mf++)
      afD[mf] = *(const bf16x8*)&lds[tbo + a_off + (4 + mf) * 1024 + 512];
    SB();
    // MFMA3: mf0-3 x nf0-3, kk1   (waits R3)
    __builtin_amdgcn_s_setprio(1);
    #pragma unroll
    for (int mf = 0; mf < 4; mf++)
      #pragma unroll
      for (int nf = 0; nf < 4; nf++)
        acc[mf][nf] = __builtin_amdgcn_mfma_f32_16x16x32_bf16(bfB[nf], afC[mf], acc[mf][nf], 0, 0, 0);
    __builtin_amdgcn_s_setprio(0);
    SB();
    // MFMA4: mf4-7 x nf0-3, kk1   (waits R4 -> full DS drain)
    __builtin_amdgcn_s_setprio(1);
    #pragma unroll
    for (int mf = 0; mf < 4; mf++)
      #pragma unroll
      for (int nf = 0; nf < 4; nf++)
        acc[4 + mf][nf] = __builtin_amdgcn_mfma_f32_16x16x32_bf16(bfB[nf], afD[mf], acc[4 + mf][nf], 0, 0, 0);
    __builtin_amdgcn_s_setprio(0);
    SB();
    __builtin_amdgcn_s_barrier();
    SB();
  }
  asm volatile("s_waitcnt vmcnt(0)" ::: "memory");

  // epilogue: lane holds C[row][colb..colb+3]
  const int rowl = m0 + wr * 128 + (l & 15);
  const int coll = n0 + wc * 64 + (l >> 4) * 4;
  const int seg = (OUTMODE == 2) ? (n0 >> 11) : 0;
  unsigned short* outseg = (unsigned short*)Cout +
      (OUTMODE == 2 ? (size_t)seg * M * 2048 : 0);
  #pragma unroll
  for (int mf = 0; mf < 8; mf++) {
    const int row = rowl + mf * 16;
    #pragma unroll
    for (int nf = 0; nf < 4; nf++) {
      const int colb = coll + nf * 16;
      const float4 bv = *(const float4*)(bias + colb);
      float v0 = acc[mf][nf][0] + bv.x;
      float v1 = acc[mf][nf][1] + bv.y;
      float v2 = acc[mf][nf][2] + bv.z;
      float v3 = acc[mf][nf][3] + bv.w;
      if (OUTMODE == 2) {
        if (seg == 2) {
          v0 = tanhf_(v0); v1 = tanhf_(v1); v2 = tanhf_(v2); v3 = tanhf_(v3);
        } else {
          v0 = sigmoidf_(v0); v1 = sigmoidf_(v1); v2 = sigmoidf_(v2); v3 = sigmoidf_(v3);
        }
        uint2 pk = {pack2(v0, v1), pack2(v2, v3)};
        *(uint2*)(outseg + (size_t)row * 2048 + (colb & 2047)) = pk;
      } else {
        uint2 pk = {pack2(v0, v1), pack2(v2, v3)};
        *(uint2*)((unsigned short*)Cout + (size_t)row * N + colb) = pk;
      }
    }
  }
}

// ---------------------------------------------------------------------------
// 128x128 GEMM (old structure) — kept for the Wo GEMM (N=1024 grid shape).
// OUTMODE 1: fp32 + residual.
// ---------------------------------------------------------------------------
template <int ACT, int OUTMODE>
__global__ __launch_bounds__(256) void gemm_bt(
    const unsigned short* __restrict__ A, const unsigned short* __restrict__ Bt,
    const float* __restrict__ bias, void* __restrict__ Cout,
    const float* __restrict__ resid, int M, int N, int K) {
  __shared__ unsigned short Alds[128 * 32];
  __shared__ unsigned short Blds[128 * 32];
  const int tid = threadIdx.x;
  const int m0 = blockIdx.y * 128, n0 = blockIdx.x * 128;
  const int l = tid & 63, w = tid >> 6;
  const int wr = w >> 1, wc = w & 1;

  f32x4 acc[4][4];
  #pragma unroll
  for (int i = 0; i < 4; i++)
    #pragma unroll
    for (int j = 0; j < 4; j++) acc[i][j] = (f32x4){0.f, 0.f, 0.f, 0.f};

  const int c0 = tid, c1 = tid + 256;
  const unsigned short* Ag0 = A + (size_t)(m0 + (c0 >> 2)) * K + (c0 & 3) * 8;
  const unsigned short* Ag1 = A + (size_t)(m0 + (c1 >> 2)) * K + (c1 & 3) * 8;
  const unsigned short* Bg0 = Bt + (size_t)(n0 + (c0 >> 2)) * K + (c0 & 3) * 8;
  const unsigned short* Bg1 = Bt + (size_t)(n0 + (c1 >> 2)) * K + (c1 & 3) * 8;
  const int frag_off = (l & 15) * 32 + (l >> 4) * 8;

  for (int k0 = 0; k0 < K; k0 += 32) {
    __builtin_amdgcn_global_load_lds(GPTR(Ag0 + k0), LPTR(&Alds[c0 * 8]), 16, 0, 0);
    __builtin_amdgcn_global_load_lds(GPTR(Ag1 + k0), LPTR(&Alds[c1 * 8]), 16, 0, 0);
    __builtin_amdgcn_global_load_lds(GPTR(Bg0 + k0), LPTR(&Blds[c0 * 8]), 16, 0, 0);
    __builtin_amdgcn_global_load_lds(GPTR(Bg1 + k0), LPTR(&Blds[c1 * 8]), 16, 0, 0);
    __syncthreads();
    bf16x8 af[4], bfv[4];
    #pragma unroll
    for (int m = 0; m < 4; m++)
      af[m] = *(const bf16x8*)(&Alds[(wr * 64 + m * 16) * 32 + frag_off]);
    #pragma unroll
    for (int n = 0; n < 4; n++)
      bfv[n] = *(const bf16x8*)(&Blds[(wc * 64 + n * 16) * 32 + frag_off]);
    #pragma unroll
    for (int m = 0; m < 4; m++)
      #pragma unroll
      for (int n = 0; n < 4; n++)
        acc[m][n] = __builtin_amdgcn_mfma_f32_16x16x32_bf16(af[m], bfv[n], acc[m][n], 0, 0, 0);
    __syncthreads();
  }

  #pragma unroll
  for (int n = 0; n < 4; n++) {
    const int col = n0 + wc * 64 + n * 16 + (l & 15);
    const float bv = bias[col];
    #pragma unroll
    for (int m = 0; m < 4; m++) {
      const int rowb = m0 + wr * 64 + m * 16 + (l >> 4) * 4;
      #pragma unroll
      for (int r = 0; r < 4; r++) {
        float v = acc[m][n][r] + bv;
        if (ACT == 1) v = sigmoidf_(v);
        else if (ACT == 2) v = tanhf_(v);
        const size_t idx = (size_t)(rowb + r) * N + col;
        if (OUTMODE == 0) ((unsigned short*)Cout)[idx] = f2b(v);
        else ((float*)Cout)[idx] = v + resid[idx];
      }
    }
  }
}

// ---------------------------------------------------------------------------
// Causal depthwise conv (K=3) + SiLU + gate.  proj bf16 [B*S][2*INNER].
// ---------------------------------------------------------------------------
__global__ __launch_bounds__(256) void conv_gate_kernel(
    const unsigned short* __restrict__ proj, const float* __restrict__ conv_w,
    const float* __restrict__ conv_b, unsigned short* __restrict__ u) {
  const size_t idx = ((size_t)blockIdx.x * 256 + threadIdx.x) * 8;
  const int d = (int)(idx & (INNER - 1));
  const size_t bt = idx >> 11;
  const int t = (int)(bt & (SS - 1));
  const size_t rowbase = bt * (2 * INNER);
  const ushort8 zero = {0, 0, 0, 0, 0, 0, 0, 0};
  ushort8 p0 = *(const ushort8*)(proj + rowbase + d);
  ushort8 p1 = zero, p2 = zero;
  if (t >= 1) p1 = *(const ushort8*)(proj + rowbase - 2 * INNER + d);
  if (t >= 2) p2 = *(const ushort8*)(proj + rowbase - 4 * INNER + d);
  ushort8 g = *(const ushort8*)(proj + rowbase + INNER + d);
  ushort8 res;
  #pragma unroll
  for (int j = 0; j < 8; j++) {
    const int dj = d + j;
    float sv = conv_b[dj] + conv_w[dj * 3] * b2f(p2[j]) +
               conv_w[dj * 3 + 1] * b2f(p1[j]) + conv_w[dj * 3 + 2] * b2f(p0[j]);
    float uu = sv * sigmoidf_(sv) * sigmoidf_(b2f(g[j]));
    res[j] = f2b(uu);
  }
  *(ushort8*)(u + idx) = res;
}

// ---------------------------------------------------------------------------
// Chunked parallel scan, 3 phases.
// ---------------------------------------------------------------------------
__global__ __launch_bounds__(256) void scan_phase1(
    const unsigned short* __restrict__ a, const unsigned short* __restrict__ b,
    const unsigned short* __restrict__ u,
    float* __restrict__ P, float* __restrict__ S) {
  const int g = blockIdx.x * 256 + threadIdx.x;   // 65536 threads
  const int ch = (g & (INNER / 4 - 1)) * 4;
  const int chunk = (g >> 9) & (NCHK - 1);
  const int bb = g >> 14;
  size_t base = ((size_t)bb * SS + (size_t)chunk * CHUNK) * INNER + ch;
  float st0 = 0.f, st1 = 0.f, st2 = 0.f, st3 = 0.f;
  float p0 = 1.f, p1 = 1.f, p2 = 1.f, p3 = 1.f;
  for (int t = 0; t < CHUNK; t++) {
    const ushort4v av = *(const ushort4v*)(a + base);
    const ushort4v bv = *(const ushort4v*)(b + base);
    const ushort4v uv = *(const ushort4v*)(u + base);
    const float a0 = b2f(av[0]), a1 = b2f(av[1]), a2 = b2f(av[2]), a3 = b2f(av[3]);
    st0 = fmaf(a0, st0, b2f(bv[0]) * b2f(uv[0])); p0 *= a0;
    st1 = fmaf(a1, st1, b2f(bv[1]) * b2f(uv[1])); p1 *= a1;
    st2 = fmaf(a2, st2, b2f(bv[2]) * b2f(uv[2])); p2 *= a2;
    st3 = fmaf(a3, st3, b2f(bv[3]) * b2f(uv[3])); p3 *= a3;
    base += INNER;
  }
  const size_t o = ((size_t)bb * NCHK + chunk) * INNER + ch;
  *(float4*)(P + o) = (float4){p0, p1, p2, p3};
  *(float4*)(S + o) = (float4){st0, st1, st2, st3};
}

__global__ __launch_bounds__(256) void scan_phase2(
    const float* __restrict__ P, const float* __restrict__ S,
    float* __restrict__ Carry) {
  const int g = blockIdx.x * 256 + threadIdx.x;   // 8192 threads
  const int ch = g & (INNER - 1);
  const int bb = g >> 11;
  float carry = 0.f;
  for (int k = 0; k < NCHK; k++) {
    const size_t o = ((size_t)bb * NCHK + k) * INNER + ch;
    Carry[o] = carry;
    carry = fmaf(P[o], carry, S[o]);
  }
}

__global__ __launch_bounds__(256) void scan_phase3(
    const unsigned short* __restrict__ a, const unsigned short* __restrict__ b,
    const unsigned short* __restrict__ c, unsigned short* __restrict__ u,
    const float* __restrict__ Carry) {
  const int g = blockIdx.x * 256 + threadIdx.x;   // 65536 threads
  const int ch = (g & (INNER / 4 - 1)) * 4;
  const int chunk = (g >> 9) & (NCHK - 1);
  const int bb = g >> 14;
  size_t base = ((size_t)bb * SS + (size_t)chunk * CHUNK) * INNER + ch;
  const size_t o = ((size_t)bb * NCHK + chunk) * INNER + ch;
  const float4 cv = *(const float4*)(Carry + o);
  float st0 = cv.x, st1 = cv.y, st2 = cv.z, st3 = cv.w;
  for (int t = 0; t < CHUNK; t++) {
    const ushort4v av = *(const ushort4v*)(a + base);
    const ushort4v bv = *(const ushort4v*)(b + base);
    const ushort4v ccv = *(const ushort4v*)(c + base);
    const ushort4v uv = *(const ushort4v*)(u + base);
    const float u0 = b2f(uv[0]), u1 = b2f(uv[1]), u2 = b2f(uv[2]), u3 = b2f(uv[3]);
    st0 = fmaf(b2f(av[0]), st0, b2f(bv[0]) * u0);
    st1 = fmaf(b2f(av[1]), st1, b2f(bv[1]) * u1);
    st2 = fmaf(b2f(av[2]), st2, b2f(bv[2]) * u2);
    st3 = fmaf(b2f(av[3]), st3, b2f(bv[3]) * u3);
    ushort4v yv;
    yv[0] = f2b(fmaf(b2f(ccv[0]), st0, u0));
    yv[1] = f2b(fmaf(b2f(ccv[1]), st1, u1));
    yv[2] = f2b(fmaf(b2f(ccv[2]), st2, u2));
    yv[3] = f2b(fmaf(b2f(ccv[3]), st3, u3));
    *(ushort4v*)(u + base) = yv;
    base += INNER;
  }
}

// ---------------------------------------------------------------------------
extern "C" void kernel_launch(void* const* d_in, const int* in_sizes, int n_in,
                              void* d_out, int out_size, void* d_ws, size_t ws_size,
                              hipStream_t stream) {
  const float* x      = (const float*)d_in[0];
  const float* W_in   = (const float*)d_in[1];
  const float* b_in   = (const float*)d_in[2];
  const float* conv_w = (const float*)d_in[3];
  const float* conv_b = (const float*)d_in[4];
  const float* Wa     = (const float*)d_in[5];
  const float* ba     = (const float*)d_in[6];
  const float* Wb     = (const float*)d_in[7];
  const float* b_b    = (const float*)d_in[8];
  const float* Wc     = (const float*)d_in[9];
  const float* bc     = (const float*)d_in[10];
  const float* Wo     = (const float*)d_in[11];
  const float* bo     = (const float*)d_in[12];
  const float* gamma  = (const float*)d_in[13];
  const float* beta   = (const float*)d_in[14];
  float* out = (float*)d_out;

  const size_t M = (size_t)BB * SS;  // 8192
  char* ws = (char*)d_ws;
  size_t off = 0;
  auto alloc = [&](size_t bytes) {
    char* p = ws + off;
    off += (bytes + 255) & ~(size_t)255;
    return p;
  };
  unsigned short* WinT  = (unsigned short*)alloc((size_t)4096 * 1024 * 2);  // 8 MB
  unsigned short* WabcT = (unsigned short*)alloc((size_t)6144 * 2048 * 2);  // 24 MB
  unsigned short* WoT   = (unsigned short*)alloc((size_t)1024 * 2048 * 2);  // 4 MB
  float*          biasABC = (float*)alloc(6144 * 4);
  unsigned short* xnB   = (unsigned short*)alloc(M * DM * 2);               // 16 MB
  unsigned short* uB    = (unsigned short*)alloc(M * INNER * 2);            // 32 MB
  unsigned short* abc   = (unsigned short*)alloc(3 * M * INNER * 2);        // 96 MB
  unsigned short* proj = abc;
  unsigned short* aB = abc;
  unsigned short* bB = abc + M * INNER;
  unsigned short* cB = abc + 2 * M * INNER;
  float* Pbuf  = (float*)xnB;          // xnB dead after proj GEMM
  float* Sbuf  = Pbuf + (size_t)BB * NCHK * INNER;
  float* Carry = Sbuf + (size_t)BB * NCHK * INNER;

  hipMemcpyAsync(biasABC,        ba,  2048 * 4, hipMemcpyDeviceToDevice, stream);
  hipMemcpyAsync(biasABC + 2048, b_b, 2048 * 4, hipMemcpyDeviceToDevice, stream);
  hipMemcpyAsync(biasABC + 4096, bc,  2048 * 4, hipMemcpyDeviceToDevice, stream);

  const dim3 tb(32, 8);
  transpose_cast_kernel<<<dim3(128, 32), tb, 0, stream>>>(W_in, WinT, 1024, 4096);
  transpose_cast_kernel<<<dim3(64, 64), tb, 0, stream>>>(Wa, WabcT, 2048, 2048);
  transpose_cast_kernel<<<dim3(64, 64), tb, 0, stream>>>(Wb, WabcT + 2048 * 2048, 2048, 2048);
  transpose_cast_kernel<<<dim3(64, 64), tb, 0, stream>>>(Wc, WabcT + 2 * 2048 * 2048, 2048, 2048);
  transpose_cast_kernel<<<dim3(32, 64), tb, 0, stream>>>(Wo, WoT, 2048, 1024);

  layernorm_kernel<<<M, 256, 0, stream>>>(x, gamma, beta, xnB);

  // proj = xn @ W_in + b_in            [8192 x 4096], grid 16x32 = 512
  gemm64<0><<<dim3(512), 512, 0, stream>>>(
      xnB, WinT, b_in, proj, M, 4096, 1024, 16);

  // u = silu(conv(projected)) * sigmoid(gate)
  conv_gate_kernel<<<(M * INNER) / (256 * 8), 256, 0, stream>>>(proj, conv_w, conv_b, uB);

  // a,b,c fused: [8192 x 6144], grid 24x32 = 768
  gemm64<2><<<dim3(768), 512, 0, stream>>>(
      uB, WabcT, biasABC, abc, M, 6144, 2048, 24);

  // chunked scan (y overwrites u)
  scan_phase1<<<256, 256, 0, stream>>>(aB, bB, uB, Pbuf, Sbuf);
  scan_phase2<<<32, 256, 0, stream>>>(Pbuf, Sbuf, Carry);
  scan_phase3<<<256, 256, 0, stream>>>(aB, bB, cB, uB, Carry);

  // out = x + y @ Wo + bo              [8192 x 1024] fp32
  gemm_bt<0, 1><<<dim3(8, 64), 256, 0, stream>>>(
      uB, WoT, bo, out, x, M, 1024, 2048);
}

// Round 11
// 462.760 us; speedup vs baseline: 1.2783x; 1.1331x over previous
//
#include <hip/hip_runtime.h>
#include <hip/hip_bf16.h>
#include <cstdint>
#include <cstddef>

#define BB 4
#define SS 2048
#define DM 1024
#define INNER 2048
#define CHUNK 64
#define NCHK (SS / CHUNK)  // 32

typedef __attribute__((ext_vector_type(8))) __bf16 bf16x8;
typedef __attribute__((ext_vector_type(4))) float f32x4;
typedef __attribute__((ext_vector_type(8))) unsigned short ushort8;
typedef __attribute__((ext_vector_type(4))) unsigned short ushort4v;

#define GPTR(p) ((const __attribute__((address_space(1))) void*)(p))
#define LPTR(p) ((__attribute__((address_space(3))) void*)(p))
#define SB() __builtin_amdgcn_sched_barrier(0)

// fp8 pre-scales (powers of 2; undone in GEMM epilogue)
#define U_SCALE 128.0f
#define W_SCALE 32.0f
#define ABC_SCALE_INV (1.0f / (128.0f * 32.0f))

__device__ inline float b2f(unsigned short h) {
  union { unsigned u; float f; } v; v.u = ((unsigned)h) << 16; return v.f;
}
__device__ inline unsigned short f2b(float f) {
  unsigned u = __float_as_uint(f);
  u += 0x7fff + ((u >> 16) & 1);   // round-to-nearest-even
  return (unsigned short)(u >> 16);
}
__device__ inline unsigned pack2(float lo, float hi) {
  return (unsigned)f2b(lo) | ((unsigned)f2b(hi) << 16);
}
__device__ inline float sigmoidf_(float x) { return 1.0f / (1.0f + __expf(-x)); }
__device__ inline float tanhf_(float x) { return 2.0f / (1.0f + __expf(-2.0f * x)) - 1.0f; }

// ---------------------------------------------------------------------------
// Transpose + cast: src fp32 [R][C] -> dst bf16 [C][R]
// ---------------------------------------------------------------------------
__global__ void transpose_cast_kernel(const float* __restrict__ src,
                                      unsigned short* __restrict__ dst,
                                      int R, int C) {
  __shared__ float tile[32][33];
  const int c0 = blockIdx.x * 32, r0 = blockIdx.y * 32;
  const int tx = threadIdx.x, ty = threadIdx.y;  // (32,8)
  #pragma unroll
  for (int j = ty; j < 32; j += 8)
    tile[j][tx] = src[(size_t)(r0 + j) * C + c0 + tx];
  __syncthreads();
  #pragma unroll
  for (int j = ty; j < 32; j += 8)
    dst[(size_t)(c0 + j) * R + r0 + tx] = f2b(tile[tx][j]);
}

// ---------------------------------------------------------------------------
// Transpose + cast to fp8 e4m3 (scaled): src fp32 [R][C] -> dst fp8 [C][R]
// ---------------------------------------------------------------------------
__global__ void transpose_cast_fp8_kernel(const float* __restrict__ src,
                                          unsigned char* __restrict__ dst,
                                          int R, int C, float scale) {
  __shared__ float tile[32][33];
  const int c0 = blockIdx.x * 32, r0 = blockIdx.y * 32;
  const int tx = threadIdx.x, ty = threadIdx.y;  // (32,8)
  #pragma unroll
  for (int j = ty; j < 32; j += 8)
    tile[j][tx] = src[(size_t)(r0 + j) * C + c0 + tx];
  __syncthreads();
  #pragma unroll
  for (int j = ty; j < 32; j += 8) {
    const int w = __builtin_amdgcn_cvt_pk_fp8_f32(tile[tx][j] * scale, 0.f, 0, 0);
    dst[(size_t)(c0 + j) * R + r0 + tx] = (unsigned char)(w & 0xff);
  }
}

// ---------------------------------------------------------------------------
// LayerNorm: x fp32 [8192][1024] -> xn bf16
// ---------------------------------------------------------------------------
__global__ __launch_bounds__(256) void layernorm_kernel(
    const float* __restrict__ x, const float* __restrict__ gamma,
    const float* __restrict__ beta, unsigned short* __restrict__ out) {
  const int row = blockIdx.x;
  const int tid = threadIdx.x;
  const float4 v = *(const float4*)(x + (size_t)row * DM + tid * 4);
  float s = v.x + v.y + v.z + v.w;
  #pragma unroll
  for (int o = 32; o >= 1; o >>= 1) s += __shfl_down(s, o, 64);
  __shared__ float red[8];
  const int wid = tid >> 6, lane = tid & 63;
  if (lane == 0) red[wid] = s;
  __syncthreads();
  const float mu = (red[0] + red[1] + red[2] + red[3]) * (1.f / DM);
  const float d0 = v.x - mu, d1 = v.y - mu, d2 = v.z - mu, d3 = v.w - mu;
  float sq = d0 * d0 + d1 * d1 + d2 * d2 + d3 * d3;
  #pragma unroll
  for (int o = 32; o >= 1; o >>= 1) sq += __shfl_down(sq, o, 64);
  if (lane == 0) red[4 + wid] = sq;
  __syncthreads();
  const float var = (red[4] + red[5] + red[6] + red[7]) * (1.f / DM);
  const float rs = rsqrtf(var + 1e-5f);
  const int c0 = tid * 4;
  ushort4v o4;
  o4[0] = f2b(d0 * rs * gamma[c0 + 0] + beta[c0 + 0]);
  o4[1] = f2b(d1 * rs * gamma[c0 + 1] + beta[c0 + 1]);
  o4[2] = f2b(d2 * rs * gamma[c0 + 2] + beta[c0 + 2]);
  o4[3] = f2b(d3 * rs * gamma[c0 + 3] + beta[c0 + 3]);
  *(ushort4v*)(out + (size_t)row * DM + c0) = o4;
}

// ---------------------------------------------------------------------------
// bf16 256x256 GEMM, BK=64 (R9 structure, unchanged) — used for proj.
// ---------------------------------------------------------------------------
template <int OUTMODE>
__global__ __launch_bounds__(512, 1) void gemm64(
    const unsigned short* __restrict__ A, const unsigned short* __restrict__ Bt,
    const float* __restrict__ bias, void* __restrict__ Cout,
    int M, int N, int K, int nbx) {
  __shared__ unsigned short lds[2 * 32768];  // 128 KB
  const int tid = threadIdx.x;
  const int nwg = gridDim.x;
  const int cpx = nwg >> 3;
  const int bid = blockIdx.x;
  const int swz = (bid & 7) * cpx + (bid >> 3);
  const int m0 = (swz / nbx) * 256, n0 = (swz % nbx) * 256;

  const int l = tid & 63, w = tid >> 6;
  const int wr = w >> 2, wc = w & 3;
  const int NT = K >> 6;

  const int a_off = (wr * 8) * 1024 + (l >> 4) * 128 + (l & 15) * 8;
  const int b_off = 16384 + (wc * 4) * 1024 + (l >> 4) * 128 + (l & 15) * 8;

  f32x4 acc[8][4];
  #pragma unroll
  for (int i = 0; i < 8; i++)
    #pragma unroll
    for (int j = 0; j < 4; j++) acc[i][j] = (f32x4){0.f, 0.f, 0.f, 0.f};

  const int r0 = ((tid >> 7) << 4) | (tid & 15);
  const int s0 = (tid >> 4) & 7;
  const unsigned short* Abase = A + (size_t)(m0 + r0) * K + s0 * 8;
  const unsigned short* Bbase = Bt + (size_t)(n0 + r0) * K + s0 * 8;
  const size_t rs64 = (size_t)64 * K;

  auto stageA = [&](int kt, int h) {
    int ktw = kt; if (ktw >= NT) ktw -= NT;
    const int k0 = ktw << 6;
    const int bo = (kt & 1) * 32768 + h * 8192 + tid * 8;
    const unsigned short* src = Abase + (size_t)(h * 128) * K + k0;
    __builtin_amdgcn_global_load_lds(GPTR(src), LPTR(&lds[bo]), 16, 0, 0);
    __builtin_amdgcn_global_load_lds(GPTR(src + rs64), LPTR(&lds[bo + 4096]), 16, 0, 0);
  };
  auto stageB = [&](int kt, int h) {
    int ktw = kt; if (ktw >= NT) ktw -= NT;
    const int k0 = ktw << 6;
    const int bo = (kt & 1) * 32768 + 16384 + h * 8192 + tid * 8;
    const unsigned short* src = Bbase + (size_t)(h * 128) * K + k0;
    __builtin_amdgcn_global_load_lds(GPTR(src), LPTR(&lds[bo]), 16, 0, 0);
    __builtin_amdgcn_global_load_lds(GPTR(src + rs64), LPTR(&lds[bo + 4096]), 16, 0, 0);
  };

  stageA(0, 0); stageA(0, 1); stageB(0, 0); stageB(0, 1);

  for (int t = 0; t < NT; t++) {
    const int tbo = (t & 1) * 32768;
    bf16x8 bfA[4], afA[4], afB[4], bfB[4], afC[4], afD[4];

    stageA(t + 1, 0); stageA(t + 1, 1);
    SB();
    asm volatile("s_waitcnt vmcnt(4)" ::: "memory");
    SB();
    __builtin_amdgcn_s_barrier();
    SB();
    #pragma unroll
    for (int nf = 0; nf < 4; nf++)
      bfA[nf] = *(const bf16x8*)&lds[tbo + b_off + nf * 1024];
    #pragma unroll
    for (int mf = 0; mf < 4; mf++)
      afA[mf] = *(const bf16x8*)&lds[tbo + a_off + mf * 1024];
    SB();
    #pragma unroll
    for (int mf = 0; mf < 4; mf++)
      afB[mf] = *(const bf16x8*)&lds[tbo + a_off + (4 + mf) * 1024];
    SB();
    __builtin_amdgcn_s_setprio(1);
    #pragma unroll
    for (int mf = 0; mf < 4; mf++)
      #pragma unroll
      for (int nf = 0; nf < 4; nf++)
        acc[mf][nf] = __builtin_amdgcn_mfma_f32_16x16x32_bf16(bfA[nf], afA[mf], acc[mf][nf], 0, 0, 0);
    __builtin_amdgcn_s_setprio(0);
    SB();
    stageB(t + 1, 0); stageB(t + 1, 1);
    SB();
    #pragma unroll
    for (int nf = 0; nf < 4; nf++)
      bfB[nf] = *(const bf16x8*)&lds[tbo + b_off + nf * 1024 + 512];
    #pragma unroll
    for (int mf = 0; mf < 4; mf++)
      afC[mf] = *(const bf16x8*)&lds[tbo + a_off + mf * 1024 + 512];
    SB();
    __builtin_amdgcn_s_setprio(1);
    #pragma unroll
    for (int mf = 0; mf < 4; mf++)
      #pragma unroll
      for (int nf = 0; nf < 4; nf++)
        acc[4 + mf][nf] = __builtin_amdgcn_mfma_f32_16x16x32_bf16(bfA[nf], afB[mf], acc[4 + mf][nf], 0, 0, 0);
    __builtin_amdgcn_s_setprio(0);
    SB();
    #pragma unroll
    for (int mf = 0; mf < 4; mf++)
      afD[mf] = *(const bf16x8*)&lds[tbo + a_off + (4 + mf) * 1024 + 512];
    SB();
    __builtin_amdgcn_s_setprio(1);
    #pragma unroll
    for (int mf = 0; mf < 4; mf++)
      #pragma unroll
      for (int nf = 0; nf < 4; nf++)
        acc[mf][nf] = __builtin_amdgcn_mfma_f32_16x16x32_bf16(bfB[nf], afC[mf], acc[mf][nf], 0, 0, 0);
    __builtin_amdgcn_s_setprio(0);
    SB();
    __builtin_amdgcn_s_setprio(1);
    #pragma unroll
    for (int mf = 0; mf < 4; mf++)
      #pragma unroll
      for (int nf = 0; nf < 4; nf++)
        acc[4 + mf][nf] = __builtin_amdgcn_mfma_f32_16x16x32_bf16(bfB[nf], afD[mf], acc[4 + mf][nf], 0, 0, 0);
    __builtin_amdgcn_s_setprio(0);
    SB();
    __builtin_amdgcn_s_barrier();
    SB();
  }
  asm volatile("s_waitcnt vmcnt(0)" ::: "memory");

  const int rowl = m0 + wr * 128 + (l & 15);
  const int coll = n0 + wc * 64 + (l >> 4) * 4;
  #pragma unroll
  for (int mf = 0; mf < 8; mf++) {
    const int row = rowl + mf * 16;
    #pragma unroll
    for (int nf = 0; nf < 4; nf++) {
      const int colb = coll + nf * 16;
      const float4 bv = *(const float4*)(bias + colb);
      float v0 = acc[mf][nf][0] + bv.x;
      float v1 = acc[mf][nf][1] + bv.y;
      float v2 = acc[mf][nf][2] + bv.z;
      float v3 = acc[mf][nf][3] + bv.w;
      uint2 pk = {pack2(v0, v1), pack2(v2, v3)};
      *(uint2*)((unsigned short*)Cout + (size_t)row * N + colb) = pk;
    }
  }
}

// ---------------------------------------------------------------------------
// FP8 e4m3 256x256 GEMM, BK=64 — used for the fused abc GEMM.
// Same schedule/ledger as gemm64; all memory-side volumes HALVED.
// LDS byte layout per 16KB region: addr = rb*1024 + s*256 + r*16
//   (rb=row>>4, s=k>>4 [16-elem slots], r=row&15) -> staging units of 16B are
//   row-contiguous in GLOBAL (16 consecutive k of one row): global_load_lds ok.
// Fragment (8 fp8, ds_read_b64, lane-linear 2-way=free):
//   a_off = wr*8192 + ((l>>4)>>1)*256 + (l&15)*16 + ((l>>4)&1)*8; +mf*1024 +kk*512
// vmcnt ledger: 2 loads/stage. Prologue A0+B0=4. Tile top: +A(t+1)=6;
// vmcnt(2) drains A(t),B(t), leaves A(t+1). Mid: +B(t+1)=4. Never drains.
// Epilogue: v = acc*ABC_SCALE_INV + bias, then seg activation (abc-fused).
// ---------------------------------------------------------------------------
__global__ __launch_bounds__(512, 1) void gemm64_fp8_abc(
    const unsigned char* __restrict__ A, const unsigned char* __restrict__ Bt,
    const float* __restrict__ bias, unsigned short* __restrict__ Cout,
    int M, int N, int K, int nbx) {
  __shared__ __align__(16) unsigned char lds8[2 * 32768];  // 64 KB
  const int tid = threadIdx.x;
  const int nwg = gridDim.x;
  const int cpx = nwg >> 3;
  const int bid = blockIdx.x;
  const int swz = (bid & 7) * cpx + (bid >> 3);
  const int m0 = (swz / nbx) * 256, n0 = (swz % nbx) * 256;

  const int l = tid & 63, w = tid >> 6;
  const int wr = w >> 2, wc = w & 3;          // 2(M) x 4(N)
  const int NT = K >> 6;                      // K-tiles of 64

  const int lane_tail = ((l >> 4) >> 1) * 256 + (l & 15) * 16 + ((l >> 4) & 1) * 8;
  const int a_off = wr * 8192 + lane_tail;            // + mf*1024 + kk*512
  const int b_off = 16384 + wc * 4096 + lane_tail;    // + nf*1024 + kk*512

  f32x4 acc[8][4];
  #pragma unroll
  for (int i = 0; i < 8; i++)
    #pragma unroll
    for (int j = 0; j < 4; j++) acc[i][j] = (f32x4){0.f, 0.f, 0.f, 0.f};

  // staging: unit u(16B): rb=u>>6, s=(u>>4)&3, r=u&15; thread covers tid, tid+512
  const int ru = ((tid >> 6) << 4) | (tid & 15);
  const int su = (tid >> 4) & 3;
  const unsigned char* Af0 = A + (size_t)(m0 + ru) * K + su * 16;
  const unsigned char* Bf0 = Bt + (size_t)(n0 + ru) * K + su * 16;
  const size_t rs128 = (size_t)128 * K;

  auto stageA = [&](int kt) {
    int ktw = kt; if (ktw >= NT) ktw -= NT;
    const int k0 = ktw << 6;
    const int bo = (kt & 1) * 32768;
    __builtin_amdgcn_global_load_lds(GPTR(Af0 + k0), LPTR(&lds8[bo + tid * 16]), 16, 0, 0);
    __builtin_amdgcn_global_load_lds(GPTR(Af0 + rs128 + k0), LPTR(&lds8[bo + (tid + 512) * 16]), 16, 0, 0);
  };
  auto stageB = [&](int kt) {
    int ktw = kt; if (ktw >= NT) ktw -= NT;
    const int k0 = ktw << 6;
    const int bo = (kt & 1) * 32768 + 16384;
    __builtin_amdgcn_global_load_lds(GPTR(Bf0 + k0), LPTR(&lds8[bo + tid * 16]), 16, 0, 0);
    __builtin_amdgcn_global_load_lds(GPTR(Bf0 + rs128 + k0), LPTR(&lds8[bo + (tid + 512) * 16]), 16, 0, 0);
  };

  stageA(0); stageB(0);   // 4 outstanding

  for (int t = 0; t < NT; t++) {
    const int tbo = (t & 1) * 32768;
    unsigned long long bfA[4], afA[4], afB[4], bfB[4], afC[4], afD[4];

    // boundary: stage A(t+1) [6 out]; vmcnt(2) -> tile t resident, A(t+1) flies
    stageA(t + 1);
    SB();
    asm volatile("s_waitcnt vmcnt(2)" ::: "memory");
    SB();
    __builtin_amdgcn_s_barrier();
    SB();
    #pragma unroll
    for (int nf = 0; nf < 4; nf++)
      bfA[nf] = *(const unsigned long long*)&lds8[tbo + b_off + nf * 1024];
    #pragma unroll
    for (int mf = 0; mf < 4; mf++)
      afA[mf] = *(const unsigned long long*)&lds8[tbo + a_off + mf * 1024];
    SB();
    #pragma unroll
    for (int mf = 0; mf < 4; mf++)
      afB[mf] = *(const unsigned long long*)&lds8[tbo + a_off + (4 + mf) * 1024];
    SB();
    __builtin_amdgcn_s_setprio(1);
    #pragma unroll
    for (int mf = 0; mf < 4; mf++)
      #pragma unroll
      for (int nf = 0; nf < 4; nf++)
        acc[mf][nf] = __builtin_amdgcn_mfma_f32_16x16x32_fp8_fp8(
            (long long)bfA[nf], (long long)afA[mf], acc[mf][nf], 0, 0, 0);
    __builtin_amdgcn_s_setprio(0);
    SB();
    stageB(t + 1);
    SB();
    #pragma unroll
    for (int nf = 0; nf < 4; nf++)
      bfB[nf] = *(const unsigned long long*)&lds8[tbo + b_off + nf * 1024 + 512];
    #pragma unroll
    for (int mf = 0; mf < 4; mf++)
      afC[mf] = *(const unsigned long long*)&lds8[tbo + a_off + mf * 1024 + 512];
    SB();
    __builtin_amdgcn_s_setprio(1);
    #pragma unroll
    for (int mf = 0; mf < 4; mf++)
      #pragma unroll
      for (int nf = 0; nf < 4; nf++)
        acc[4 + mf][nf] = __builtin_amdgcn_mfma_f32_16x16x32_fp8_fp8(
            (long long)bfA[nf], (long long)afB[mf], acc[4 + mf][nf], 0, 0, 0);
    __builtin_amdgcn_s_setprio(0);
    SB();
    #pragma unroll
    for (int mf = 0; mf < 4; mf++)
      afD[mf] = *(const unsigned long long*)&lds8[tbo + a_off + (4 + mf) * 1024 + 512];
    SB();
    __builtin_amdgcn_s_setprio(1);
    #pragma unroll
    for (int mf = 0; mf < 4; mf++)
      #pragma unroll
      for (int nf = 0; nf < 4; nf++)
        acc[mf][nf] = __builtin_amdgcn_mfma_f32_16x16x32_fp8_fp8(
            (long long)bfB[nf], (long long)afC[mf], acc[mf][nf], 0, 0, 0);
    __builtin_amdgcn_s_setprio(0);
    SB();
    __builtin_amdgcn_s_setprio(1);
    #pragma unroll
    for (int mf = 0; mf < 4; mf++)
      #pragma unroll
      for (int nf = 0; nf < 4; nf++)
        acc[4 + mf][nf] = __builtin_amdgcn_mfma_f32_16x16x32_fp8_fp8(
            (long long)bfB[nf], (long long)afD[mf], acc[4 + mf][nf], 0, 0, 0);
    __builtin_amdgcn_s_setprio(0);
    SB();
    __builtin_amdgcn_s_barrier();
    SB();
  }
  asm volatile("s_waitcnt vmcnt(0)" ::: "memory");

  // epilogue: abc-fused; lane holds C[row][colb..colb+3]
  const int rowl = m0 + wr * 128 + (l & 15);
  const int coll = n0 + wc * 64 + (l >> 4) * 4;
  const int seg = n0 >> 11;
  unsigned short* outseg = Cout + (size_t)seg * M * 2048;
  #pragma unroll
  for (int mf = 0; mf < 8; mf++) {
    const int row = rowl + mf * 16;
    #pragma unroll
    for (int nf = 0; nf < 4; nf++) {
      const int colb = coll + nf * 16;
      const float4 bv = *(const float4*)(bias + colb);
      float v0 = acc[mf][nf][0] * ABC_SCALE_INV + bv.x;
      float v1 = acc[mf][nf][1] * ABC_SCALE_INV + bv.y;
      float v2 = acc[mf][nf][2] * ABC_SCALE_INV + bv.z;
      float v3 = acc[mf][nf][3] * ABC_SCALE_INV + bv.w;
      if (seg == 2) {
        v0 = tanhf_(v0); v1 = tanhf_(v1); v2 = tanhf_(v2); v3 = tanhf_(v3);
      } else {
        v0 = sigmoidf_(v0); v1 = sigmoidf_(v1); v2 = sigmoidf_(v2); v3 = sigmoidf_(v3);
      }
      uint2 pk = {pack2(v0, v1), pack2(v2, v3)};
      *(uint2*)(outseg + (size_t)row * 2048 + (colb & 2047)) = pk;
    }
  }
}

// ---------------------------------------------------------------------------
// 128x128 GEMM (old structure) — kept for the Wo GEMM.  OUTMODE 1: fp32+resid.
// ---------------------------------------------------------------------------
template <int ACT, int OUTMODE>
__global__ __launch_bounds__(256) void gemm_bt(
    const unsigned short* __restrict__ A, const unsigned short* __restrict__ Bt,
    const float* __restrict__ bias, void* __restrict__ Cout,
    const float* __restrict__ resid, int M, int N, int K) {
  __shared__ unsigned short Alds[128 * 32];
  __shared__ unsigned short Blds[128 * 32];
  const int tid = threadIdx.x;
  const int m0 = blockIdx.y * 128, n0 = blockIdx.x * 128;
  const int l = tid & 63, w = tid >> 6;
  const int wr = w >> 1, wc = w & 1;

  f32x4 acc[4][4];
  #pragma unroll
  for (int i = 0; i < 4; i++)
    #pragma unroll
    for (int j = 0; j < 4; j++) acc[i][j] = (f32x4){0.f, 0.f, 0.f, 0.f};

  const int c0 = tid, c1 = tid + 256;
  const unsigned short* Ag0 = A + (size_t)(m0 + (c0 >> 2)) * K + (c0 & 3) * 8;
  const unsigned short* Ag1 = A + (size_t)(m0 + (c1 >> 2)) * K + (c1 & 3) * 8;
  const unsigned short* Bg0 = Bt + (size_t)(n0 + (c0 >> 2)) * K + (c0 & 3) * 8;
  const unsigned short* Bg1 = Bt + (size_t)(n0 + (c1 >> 2)) * K + (c1 & 3) * 8;
  const int frag_off = (l & 15) * 32 + (l >> 4) * 8;

  for (int k0 = 0; k0 < K; k0 += 32) {
    __builtin_amdgcn_global_load_lds(GPTR(Ag0 + k0), LPTR(&Alds[c0 * 8]), 16, 0, 0);
    __builtin_amdgcn_global_load_lds(GPTR(Ag1 + k0), LPTR(&Alds[c1 * 8]), 16, 0, 0);
    __builtin_amdgcn_global_load_lds(GPTR(Bg0 + k0), LPTR(&Blds[c0 * 8]), 16, 0, 0);
    __builtin_amdgcn_global_load_lds(GPTR(Bg1 + k0), LPTR(&Blds[c1 * 8]), 16, 0, 0);
    __syncthreads();
    bf16x8 af[4], bfv[4];
    #pragma unroll
    for (int m = 0; m < 4; m++)
      af[m] = *(const bf16x8*)(&Alds[(wr * 64 + m * 16) * 32 + frag_off]);
    #pragma unroll
    for (int n = 0; n < 4; n++)
      bfv[n] = *(const bf16x8*)(&Blds[(wc * 64 + n * 16) * 32 + frag_off]);
    #pragma unroll
    for (int m = 0; m < 4; m++)
      #pragma unroll
      for (int n = 0; n < 4; n++)
        acc[m][n] = __builtin_amdgcn_mfma_f32_16x16x32_bf16(af[m], bfv[n], acc[m][n], 0, 0, 0);
    __syncthreads();
  }

  #pragma unroll
  for (int n = 0; n < 4; n++) {
    const int col = n0 + wc * 64 + n * 16 + (l & 15);
    const float bv = bias[col];
    #pragma unroll
    for (int m = 0; m < 4; m++) {
      const int rowb = m0 + wr * 64 + m * 16 + (l >> 4) * 4;
      #pragma unroll
      for (int r = 0; r < 4; r++) {
        float v = acc[m][n][r] + bv;
        if (ACT == 1) v = sigmoidf_(v);
        else if (ACT == 2) v = tanhf_(v);
        const size_t idx = (size_t)(rowb + r) * N + col;
        if (OUTMODE == 0) ((unsigned short*)Cout)[idx] = f2b(v);
        else ((float*)Cout)[idx] = v + resid[idx];
      }
    }
  }
}

// ---------------------------------------------------------------------------
// Causal depthwise conv (K=3) + SiLU + gate.  Writes u bf16 AND u fp8 (x128).
// ---------------------------------------------------------------------------
__global__ __launch_bounds__(256) void conv_gate_kernel(
    const unsigned short* __restrict__ proj, const float* __restrict__ conv_w,
    const float* __restrict__ conv_b, unsigned short* __restrict__ u,
    unsigned char* __restrict__ u8) {
  const size_t idx = ((size_t)blockIdx.x * 256 + threadIdx.x) * 8;
  const int d = (int)(idx & (INNER - 1));
  const size_t bt = idx >> 11;
  const int t = (int)(bt & (SS - 1));
  const size_t rowbase = bt * (2 * INNER);
  const ushort8 zero = {0, 0, 0, 0, 0, 0, 0, 0};
  ushort8 p0 = *(const ushort8*)(proj + rowbase + d);
  ushort8 p1 = zero, p2 = zero;
  if (t >= 1) p1 = *(const ushort8*)(proj + rowbase - 2 * INNER + d);
  if (t >= 2) p2 = *(const ushort8*)(proj + rowbase - 4 * INNER + d);
  ushort8 g = *(const ushort8*)(proj + rowbase + INNER + d);
  ushort8 res;
  float us[8];
  #pragma unroll
  for (int j = 0; j < 8; j++) {
    const int dj = d + j;
    float sv = conv_b[dj] + conv_w[dj * 3] * b2f(p2[j]) +
               conv_w[dj * 3 + 1] * b2f(p1[j]) + conv_w[dj * 3 + 2] * b2f(p0[j]);
    float uu = sv * sigmoidf_(sv) * sigmoidf_(b2f(g[j]));
    us[j] = uu;
    res[j] = f2b(uu);
  }
  *(ushort8*)(u + idx) = res;
  unsigned w0 = 0, w1 = 0;
  w0 = __builtin_amdgcn_cvt_pk_fp8_f32(us[0] * U_SCALE, us[1] * U_SCALE, (int)w0, 0);
  w0 = __builtin_amdgcn_cvt_pk_fp8_f32(us[2] * U_SCALE, us[3] * U_SCALE, (int)w0, 1);
  w1 = __builtin_amdgcn_cvt_pk_fp8_f32(us[4] * U_SCALE, us[5] * U_SCALE, (int)w1, 0);
  w1 = __builtin_amdgcn_cvt_pk_fp8_f32(us[6] * U_SCALE, us[7] * U_SCALE, (int)w1, 1);
  uint2 pk = {w0, w1};
  *(uint2*)(u8 + idx) = pk;
}

// ---------------------------------------------------------------------------
// Chunked parallel scan, 3 phases.
// ---------------------------------------------------------------------------
__global__ __launch_bounds__(256) void scan_phase1(
    const unsigned short* __restrict__ a, const unsigned short* __restrict__ b,
    const unsigned short* __restrict__ u,
    float* __restrict__ P, float* __restrict__ S) {
  const int g = blockIdx.x * 256 + threadIdx.x;   // 65536 threads
  const int ch = (g & (INNER / 4 - 1)) * 4;
  const int chunk = (g >> 9) & (NCHK - 1);
  const int bb = g >> 14;
  size_t base = ((size_t)bb * SS + (size_t)chunk * CHUNK) * INNER + ch;
  float st0 = 0.f, st1 = 0.f, st2 = 0.f, st3 = 0.f;
  float p0 = 1.f, p1 = 1.f, p2 = 1.f, p3 = 1.f;
  for (int t = 0; t < CHUNK; t++) {
    const ushort4v av = *(const ushort4v*)(a + base);
    const ushort4v bv = *(const ushort4v*)(b + base);
    const ushort4v uv = *(const ushort4v*)(u + base);
    const float a0 = b2f(av[0]), a1 = b2f(av[1]), a2 = b2f(av[2]), a3 = b2f(av[3]);
    st0 = fmaf(a0, st0, b2f(bv[0]) * b2f(uv[0])); p0 *= a0;
    st1 = fmaf(a1, st1, b2f(bv[1]) * b2f(uv[1])); p1 *= a1;
    st2 = fmaf(a2, st2, b2f(bv[2]) * b2f(uv[2])); p2 *= a2;
    st3 = fmaf(a3, st3, b2f(bv[3]) * b2f(uv[3])); p3 *= a3;
    base += INNER;
  }
  const size_t o = ((size_t)bb * NCHK + chunk) * INNER + ch;
  *(float4*)(P + o) = (float4){p0, p1, p2, p3};
  *(float4*)(S + o) = (float4){st0, st1, st2, st3};
}

__global__ __launch_bounds__(256) void scan_phase2(
    const float* __restrict__ P, const float* __restrict__ S,
    float* __restrict__ Carry) {
  const int g = blockIdx.x * 256 + threadIdx.x;   // 8192 threads
  const int ch = g & (INNER - 1);
  const int bb = g >> 11;
  float carry = 0.f;
  for (int k = 0; k < NCHK; k++) {
    const size_t o = ((size_t)bb * NCHK + k) * INNER + ch;
    Carry[o] = carry;
    carry = fmaf(P[o], carry, S[o]);
  }
}

__global__ __launch_bounds__(256) void scan_phase3(
    const unsigned short* __restrict__ a, const unsigned short* __restrict__ b,
    const unsigned short* __restrict__ c, unsigned short* __restrict__ u,
    const float* __restrict__ Carry) {
  const int g = blockIdx.x * 256 + threadIdx.x;   // 65536 threads
  const int ch = (g & (INNER / 4 - 1)) * 4;
  const int chunk = (g >> 9) & (NCHK - 1);
  const int bb = g >> 14;
  size_t base = ((size_t)bb * SS + (size_t)chunk * CHUNK) * INNER + ch;
  const size_t o = ((size_t)bb * NCHK + chunk) * INNER + ch;
  const float4 cv = *(const float4*)(Carry + o);
  float st0 = cv.x, st1 = cv.y, st2 = cv.z, st3 = cv.w;
  for (int t = 0; t < CHUNK; t++) {
    const ushort4v av = *(const ushort4v*)(a + base);
    const ushort4v bv = *(const ushort4v*)(b + base);
    const ushort4v ccv = *(const ushort4v*)(c + base);
    const ushort4v uv = *(const ushort4v*)(u + base);
    const float u0 = b2f(uv[0]), u1 = b2f(uv[1]), u2 = b2f(uv[2]), u3 = b2f(uv[3]);
    st0 = fmaf(b2f(av[0]), st0, b2f(bv[0]) * u0);
    st1 = fmaf(b2f(av[1]), st1, b2f(bv[1]) * u1);
    st2 = fmaf(b2f(av[2]), st2, b2f(bv[2]) * u2);
    st3 = fmaf(b2f(av[3]), st3, b2f(bv[3]) * u3);
    ushort4v yv;
    yv[0] = f2b(fmaf(b2f(ccv[0]), st0, u0));
    yv[1] = f2b(fmaf(b2f(ccv[1]), st1, u1));
    yv[2] = f2b(fmaf(b2f(ccv[2]), st2, u2));
    yv[3] = f2b(fmaf(b2f(ccv[3]), st3, u3));
    *(ushort4v*)(u + base) = yv;
    base += INNER;
  }
}

// ---------------------------------------------------------------------------
extern "C" void kernel_launch(void* const* d_in, const int* in_sizes, int n_in,
                              void* d_out, int out_size, void* d_ws, size_t ws_size,
                              hipStream_t stream) {
  const float* x      = (const float*)d_in[0];
  const float* W_in   = (const float*)d_in[1];
  const float* b_in   = (const float*)d_in[2];
  const float* conv_w = (const float*)d_in[3];
  const float* conv_b = (const float*)d_in[4];
  const float* Wa     = (const float*)d_in[5];
  const float* ba     = (const float*)d_in[6];
  const float* Wb     = (const float*)d_in[7];
  const float* b_b    = (const float*)d_in[8];
  const float* Wc     = (const float*)d_in[9];
  const float* bc     = (const float*)d_in[10];
  const float* Wo     = (const float*)d_in[11];
  const float* bo     = (const float*)d_in[12];
  const float* gamma  = (const float*)d_in[13];
  const float* beta   = (const float*)d_in[14];
  float* out = (float*)d_out;

  const size_t M = (size_t)BB * SS;  // 8192
  char* ws = (char*)d_ws;
  size_t off = 0;
  auto alloc = [&](size_t bytes) {
    char* p = ws + off;
    off += (bytes + 255) & ~(size_t)255;
    return p;
  };
  unsigned short* WinT   = (unsigned short*)alloc((size_t)4096 * 1024 * 2); // 8 MB
  unsigned char*  WabcF8 = (unsigned char*)alloc((size_t)6144 * 2048);     // 12 MB
  unsigned short* WoT    = (unsigned short*)alloc((size_t)1024 * 2048 * 2); // 4 MB
  float*          biasABC = (float*)alloc(6144 * 4);
  unsigned short* xnB   = (unsigned short*)alloc(M * DM * 2);              // 16 MB
  unsigned short* uB    = (unsigned short*)alloc(M * INNER * 2);           // 32 MB
  unsigned char*  u8B   = (unsigned char*)alloc(M * INNER);                // 16 MB
  unsigned short* abc   = (unsigned short*)alloc(3 * M * INNER * 2);       // 96 MB
  unsigned short* proj = abc;
  unsigned short* aB = abc;
  unsigned short* bB = abc + M * INNER;
  unsigned short* cB = abc + 2 * M * INNER;
  float* Pbuf  = (float*)xnB;          // xnB dead after proj GEMM
  float* Sbuf  = Pbuf + (size_t)BB * NCHK * INNER;
  float* Carry = Sbuf + (size_t)BB * NCHK * INNER;

  hipMemcpyAsync(biasABC,        ba,  2048 * 4, hipMemcpyDeviceToDevice, stream);
  hipMemcpyAsync(biasABC + 2048, b_b, 2048 * 4, hipMemcpyDeviceToDevice, stream);
  hipMemcpyAsync(biasABC + 4096, bc,  2048 * 4, hipMemcpyDeviceToDevice, stream);

  const dim3 tb(32, 8);
  transpose_cast_kernel<<<dim3(128, 32), tb, 0, stream>>>(W_in, WinT, 1024, 4096);
  transpose_cast_fp8_kernel<<<dim3(64, 64), tb, 0, stream>>>(Wa, WabcF8, 2048, 2048, W_SCALE);
  transpose_cast_fp8_kernel<<<dim3(64, 64), tb, 0, stream>>>(Wb, WabcF8 + 2048 * 2048, 2048, 2048, W_SCALE);
  transpose_cast_fp8_kernel<<<dim3(64, 64), tb, 0, stream>>>(Wc, WabcF8 + 2 * 2048 * 2048, 2048, 2048, W_SCALE);
  transpose_cast_kernel<<<dim3(32, 64), tb, 0, stream>>>(Wo, WoT, 2048, 1024);

  layernorm_kernel<<<M, 256, 0, stream>>>(x, gamma, beta, xnB);

  // proj = xn @ W_in + b_in            [8192 x 4096] bf16, grid 16x32 = 512
  gemm64<0><<<dim3(512), 512, 0, stream>>>(
      xnB, WinT, b_in, proj, M, 4096, 1024, 16);

  // u = silu(conv(projected)) * sigmoid(gate)  (bf16 + fp8x128 copies)
  conv_gate_kernel<<<(M * INNER) / (256 * 8), 256, 0, stream>>>(
      proj, conv_w, conv_b, uB, u8B);

  // a,b,c fused: [8192 x 6144] FP8, grid 24x32 = 768
  gemm64_fp8_abc<<<dim3(768), 512, 0, stream>>>(
      u8B, WabcF8, biasABC, abc, M, 6144, 2048, 24);

  // chunked scan (y overwrites u)
  scan_phase1<<<256, 256, 0, stream>>>(aB, bB, uB, Pbuf, Sbuf);
  scan_phase2<<<32, 256, 0, stream>>>(Pbuf, Sbuf, Carry);
  scan_phase3<<<256, 256, 0, stream>>>(aB, bB, cB, uB, Carry);

  // out = x + y @ Wo + bo              [8192 x 1024] fp32
  gemm_bt<0, 1><<<dim3(8, 64), 256, 0, stream>>>(
      uB, WoT, bo, out, x, M, 1024, 2048);
}

// Round 12
// 408.619 us; speedup vs baseline: 1.4476x; 1.1325x over previous
//
#include <hip/hip_runtime.h>
#include <hip/hip_bf16.h>
#include <cstdint>
#include <cstddef>

#define BB 4
#define SS 2048
#define DM 1024
#define INNER 2048
#define CHUNK 64
#define NCHK (SS / CHUNK)  // 32

typedef __attribute__((ext_vector_type(8))) __bf16 bf16x8;
typedef __attribute__((ext_vector_type(4))) float f32x4;
typedef __attribute__((ext_vector_type(8))) unsigned short ushort8;
typedef __attribute__((ext_vector_type(4))) unsigned short ushort4v;

#define GPTR(p) ((const __attribute__((address_space(1))) void*)(p))
#define LPTR(p) ((__attribute__((address_space(3))) void*)(p))
#define SB() __builtin_amdgcn_sched_barrier(0)

// fp8 pre-scales (powers of 2; undone in GEMM epilogues)
#define XN_SCALE 8.0f
#define WIN_SCALE 32.0f
#define PROJ_SCALE_INV (1.0f / 256.0f)
#define U_SCALE 128.0f
#define W_SCALE 32.0f
#define ABC_SCALE_INV (1.0f / 4096.0f)
#define Y_SCALE 128.0f
#define WO_SCALE 32.0f
#define WO_SCALE_INV (1.0f / 4096.0f)

__device__ inline float b2f(unsigned short h) {
  union { unsigned u; float f; } v; v.u = ((unsigned)h) << 16; return v.f;
}
__device__ inline unsigned short f2b(float f) {
  unsigned u = __float_as_uint(f);
  u += 0x7fff + ((u >> 16) & 1);   // round-to-nearest-even
  return (unsigned short)(u >> 16);
}
__device__ inline unsigned pack2(float lo, float hi) {
  return (unsigned)f2b(lo) | ((unsigned)f2b(hi) << 16);
}
__device__ inline unsigned pk_fp8x4(float a, float b, float c, float d) {
  unsigned w = 0;
  w = __builtin_amdgcn_cvt_pk_fp8_f32(a, b, (int)w, 0);
  w = __builtin_amdgcn_cvt_pk_fp8_f32(c, d, (int)w, 1);
  return w;
}
__device__ inline float sigmoidf_(float x) { return 1.0f / (1.0f + __expf(-x)); }
__device__ inline float tanhf_(float x) { return 2.0f / (1.0f + __expf(-2.0f * x)) - 1.0f; }

// ---------------------------------------------------------------------------
// Transpose + cast to fp8 e4m3 (scaled): src fp32 [R][C] -> dst fp8 [C][R]
// ---------------------------------------------------------------------------
__global__ void transpose_cast_fp8_kernel(const float* __restrict__ src,
                                          unsigned char* __restrict__ dst,
                                          int R, int C, float scale) {
  __shared__ float tile[32][33];
  const int c0 = blockIdx.x * 32, r0 = blockIdx.y * 32;
  const int tx = threadIdx.x, ty = threadIdx.y;  // (32,8)
  #pragma unroll
  for (int j = ty; j < 32; j += 8)
    tile[j][tx] = src[(size_t)(r0 + j) * C + c0 + tx];
  __syncthreads();
  #pragma unroll
  for (int j = ty; j < 32; j += 8) {
    const int w = __builtin_amdgcn_cvt_pk_fp8_f32(tile[tx][j] * scale, 0.f, 0, 0);
    dst[(size_t)(c0 + j) * R + r0 + tx] = (unsigned char)(w & 0xff);
  }
}

// ---------------------------------------------------------------------------
// LayerNorm: x fp32 [8192][1024] -> xn fp8 e4m3 (x XN_SCALE)
// ---------------------------------------------------------------------------
__global__ __launch_bounds__(256) void layernorm_kernel(
    const float* __restrict__ x, const float* __restrict__ gamma,
    const float* __restrict__ beta, unsigned char* __restrict__ out) {
  const int row = blockIdx.x;
  const int tid = threadIdx.x;
  const float4 v = *(const float4*)(x + (size_t)row * DM + tid * 4);
  float s = v.x + v.y + v.z + v.w;
  #pragma unroll
  for (int o = 32; o >= 1; o >>= 1) s += __shfl_down(s, o, 64);
  __shared__ float red[8];
  const int wid = tid >> 6, lane = tid & 63;
  if (lane == 0) red[wid] = s;
  __syncthreads();
  const float mu = (red[0] + red[1] + red[2] + red[3]) * (1.f / DM);
  const float d0 = v.x - mu, d1 = v.y - mu, d2 = v.z - mu, d3 = v.w - mu;
  float sq = d0 * d0 + d1 * d1 + d2 * d2 + d3 * d3;
  #pragma unroll
  for (int o = 32; o >= 1; o >>= 1) sq += __shfl_down(sq, o, 64);
  if (lane == 0) red[4 + wid] = sq;
  __syncthreads();
  const float var = (red[4] + red[5] + red[6] + red[7]) * (1.f / DM);
  const float rs = rsqrtf(var + 1e-5f);
  const int c0 = tid * 4;
  const float o0 = (d0 * rs * gamma[c0 + 0] + beta[c0 + 0]) * XN_SCALE;
  const float o1 = (d1 * rs * gamma[c0 + 1] + beta[c0 + 1]) * XN_SCALE;
  const float o2 = (d2 * rs * gamma[c0 + 2] + beta[c0 + 2]) * XN_SCALE;
  const float o3 = (d3 * rs * gamma[c0 + 3] + beta[c0 + 3]) * XN_SCALE;
  *(unsigned*)(out + (size_t)row * DM + c0) = pk_fp8x4(o0, o1, o2, o3);
}

// ---------------------------------------------------------------------------
// FP8 e4m3 256x256 GEMM, BK=64 (R10-verified structure).
// LDS byte layout per 16KB region: addr = rb*1024 + s*256 + r*16
//   (rb=row>>4, s=k>>4, r=row&15); staging 16B units are row-contiguous in
//   GLOBAL; fragments are lane-linear ds_read_b64.
// vmcnt ledger: 2 loads/stage; prologue A0+B0=4; top +A(t+1)=6, vmcnt(2)
// drains tile t exactly; mid +B(t+1); never drains in loop.
// Operand-swapped MFMA -> lane holds 4 consecutive C columns.
// OUTMODE 0: bf16 store (v = acc*sinv + bias).
// OUTMODE 2: abc-fused (seg0/1 sigmoid, seg2 tanh; contiguous [M][2048] segs).
// ---------------------------------------------------------------------------
template <int OUTMODE>
__global__ __launch_bounds__(512, 1) void gemm64_fp8(
    const unsigned char* __restrict__ A, const unsigned char* __restrict__ Bt,
    const float* __restrict__ bias, unsigned short* __restrict__ Cout,
    int M, int N, int K, int nbx, float sinv) {
  __shared__ __align__(16) unsigned char lds8[2 * 32768];  // 64 KB
  const int tid = threadIdx.x;
  const int nwg = gridDim.x;
  const int cpx = nwg >> 3;
  const int bid = blockIdx.x;
  const int swz = (bid & 7) * cpx + (bid >> 3);
  const int m0 = (swz / nbx) * 256, n0 = (swz % nbx) * 256;

  const int l = tid & 63, w = tid >> 6;
  const int wr = w >> 2, wc = w & 3;          // 2(M) x 4(N)
  const int NT = K >> 6;                      // K-tiles of 64

  const int lane_tail = ((l >> 4) >> 1) * 256 + (l & 15) * 16 + ((l >> 4) & 1) * 8;
  const int a_off = wr * 8192 + lane_tail;            // + mf*1024 + kk*512
  const int b_off = 16384 + wc * 4096 + lane_tail;    // + nf*1024 + kk*512

  f32x4 acc[8][4];
  #pragma unroll
  for (int i = 0; i < 8; i++)
    #pragma unroll
    for (int j = 0; j < 4; j++) acc[i][j] = (f32x4){0.f, 0.f, 0.f, 0.f};

  const int ru = ((tid >> 6) << 4) | (tid & 15);
  const int su = (tid >> 4) & 3;
  const unsigned char* Af0 = A + (size_t)(m0 + ru) * K + su * 16;
  const unsigned char* Bf0 = Bt + (size_t)(n0 + ru) * K + su * 16;
  const size_t rs128 = (size_t)128 * K;

  auto stageA = [&](int kt) {
    int ktw = kt; if (ktw >= NT) ktw -= NT;
    const int k0 = ktw << 6;
    const int bo = (kt & 1) * 32768;
    __builtin_amdgcn_global_load_lds(GPTR(Af0 + k0), LPTR(&lds8[bo + tid * 16]), 16, 0, 0);
    __builtin_amdgcn_global_load_lds(GPTR(Af0 + rs128 + k0), LPTR(&lds8[bo + (tid + 512) * 16]), 16, 0, 0);
  };
  auto stageB = [&](int kt) {
    int ktw = kt; if (ktw >= NT) ktw -= NT;
    const int k0 = ktw << 6;
    const int bo = (kt & 1) * 32768 + 16384;
    __builtin_amdgcn_global_load_lds(GPTR(Bf0 + k0), LPTR(&lds8[bo + tid * 16]), 16, 0, 0);
    __builtin_amdgcn_global_load_lds(GPTR(Bf0 + rs128 + k0), LPTR(&lds8[bo + (tid + 512) * 16]), 16, 0, 0);
  };

  stageA(0); stageB(0);   // 4 outstanding

  for (int t = 0; t < NT; t++) {
    const int tbo = (t & 1) * 32768;
    unsigned long long bfA[4], afA[4], afB[4], bfB[4], afC[4], afD[4];

    stageA(t + 1);
    SB();
    asm volatile("s_waitcnt vmcnt(2)" ::: "memory");
    SB();
    __builtin_amdgcn_s_barrier();
    SB();
    #pragma unroll
    for (int nf = 0; nf < 4; nf++)
      bfA[nf] = *(const unsigned long long*)&lds8[tbo + b_off + nf * 1024];
    #pragma unroll
    for (int mf = 0; mf < 4; mf++)
      afA[mf] = *(const unsigned long long*)&lds8[tbo + a_off + mf * 1024];
    SB();
    #pragma unroll
    for (int mf = 0; mf < 4; mf++)
      afB[mf] = *(const unsigned long long*)&lds8[tbo + a_off + (4 + mf) * 1024];
    SB();
    __builtin_amdgcn_s_setprio(1);
    #pragma unroll
    for (int mf = 0; mf < 4; mf++)
      #pragma unroll
      for (int nf = 0; nf < 4; nf++)
        acc[mf][nf] = __builtin_amdgcn_mfma_f32_16x16x32_fp8_fp8(
            (long long)bfA[nf], (long long)afA[mf], acc[mf][nf], 0, 0, 0);
    __builtin_amdgcn_s_setprio(0);
    SB();
    stageB(t + 1);
    SB();
    #pragma unroll
    for (int nf = 0; nf < 4; nf++)
      bfB[nf] = *(const unsigned long long*)&lds8[tbo + b_off + nf * 1024 + 512];
    #pragma unroll
    for (int mf = 0; mf < 4; mf++)
      afC[mf] = *(const unsigned long long*)&lds8[tbo + a_off + mf * 1024 + 512];
    SB();
    __builtin_amdgcn_s_setprio(1);
    #pragma unroll
    for (int mf = 0; mf < 4; mf++)
      #pragma unroll
      for (int nf = 0; nf < 4; nf++)
        acc[4 + mf][nf] = __builtin_amdgcn_mfma_f32_16x16x32_fp8_fp8(
            (long long)bfA[nf], (long long)afB[mf], acc[4 + mf][nf], 0, 0, 0);
    __builtin_amdgcn_s_setprio(0);
    SB();
    #pragma unroll
    for (int mf = 0; mf < 4; mf++)
      afD[mf] = *(const unsigned long long*)&lds8[tbo + a_off + (4 + mf) * 1024 + 512];
    SB();
    __builtin_amdgcn_s_setprio(1);
    #pragma unroll
    for (int mf = 0; mf < 4; mf++)
      #pragma unroll
      for (int nf = 0; nf < 4; nf++)
        acc[mf][nf] = __builtin_amdgcn_mfma_f32_16x16x32_fp8_fp8(
            (long long)bfB[nf], (long long)afC[mf], acc[mf][nf], 0, 0, 0);
    __builtin_amdgcn_s_setprio(0);
    SB();
    __builtin_amdgcn_s_setprio(1);
    #pragma unroll
    for (int mf = 0; mf < 4; mf++)
      #pragma unroll
      for (int nf = 0; nf < 4; nf++)
        acc[4 + mf][nf] = __builtin_amdgcn_mfma_f32_16x16x32_fp8_fp8(
            (long long)bfB[nf], (long long)afD[mf], acc[4 + mf][nf], 0, 0, 0);
    __builtin_amdgcn_s_setprio(0);
    SB();
    __builtin_amdgcn_s_barrier();
    SB();
  }
  asm volatile("s_waitcnt vmcnt(0)" ::: "memory");

  const int rowl = m0 + wr * 128 + (l & 15);
  const int coll = n0 + wc * 64 + (l >> 4) * 4;
  const int seg = (OUTMODE == 2) ? (n0 >> 11) : 0;
  unsigned short* outseg = Cout + (OUTMODE == 2 ? (size_t)seg * M * 2048 : 0);
  #pragma unroll
  for (int mf = 0; mf < 8; mf++) {
    const int row = rowl + mf * 16;
    #pragma unroll
    for (int nf = 0; nf < 4; nf++) {
      const int colb = coll + nf * 16;
      const float4 bv = *(const float4*)(bias + colb);
      float v0 = acc[mf][nf][0] * sinv + bv.x;
      float v1 = acc[mf][nf][1] * sinv + bv.y;
      float v2 = acc[mf][nf][2] * sinv + bv.z;
      float v3 = acc[mf][nf][3] * sinv + bv.w;
      if (OUTMODE == 2) {
        if (seg == 2) {
          v0 = tanhf_(v0); v1 = tanhf_(v1); v2 = tanhf_(v2); v3 = tanhf_(v3);
        } else {
          v0 = sigmoidf_(v0); v1 = sigmoidf_(v1); v2 = sigmoidf_(v2); v3 = sigmoidf_(v3);
        }
        uint2 pk = {pack2(v0, v1), pack2(v2, v3)};
        *(uint2*)(outseg + (size_t)row * 2048 + (colb & 2047)) = pk;
      } else {
        uint2 pk = {pack2(v0, v1), pack2(v2, v3)};
        *(uint2*)(Cout + (size_t)row * N + colb) = pk;
      }
    }
  }
}

// ---------------------------------------------------------------------------
// FP8 e4m3 256x128 GEMM for Wo (N=1024 -> grid 32x8=256 = 1 block/CU).
// 8 waves as 4(M)x2(N), wave tile 64x64, acc[4][4]. BK=64, 2x24KB buffers.
// vmcnt ledger: stageA=2, stageB=1; prologue 3; top +2 -> vmcnt(2) drains
// tile t exactly; mid +1; never drains in loop.
// Epilogue: fp32 out = acc*WO_SCALE_INV + bias + resid (float4 stores).
// ---------------------------------------------------------------------------
__global__ __launch_bounds__(512, 1) void gemm_fp8_wo(
    const unsigned char* __restrict__ A, const unsigned char* __restrict__ Bt,
    const float* __restrict__ bias, float* __restrict__ Cout,
    const float* __restrict__ resid, int M, int N, int K, int nbx) {
  __shared__ __align__(16) unsigned char lds8[2 * 24576];  // 48 KB
  const int tid = threadIdx.x;
  const int nwg = gridDim.x;
  const int cpx = nwg >> 3;
  const int bid = blockIdx.x;
  const int swz = (bid & 7) * cpx + (bid >> 3);
  const int m0 = (swz / nbx) * 256, n0 = (swz % nbx) * 128;

  const int l = tid & 63, w = tid >> 6;
  const int wr = w >> 1, wc = w & 1;          // 4(M) x 2(N)
  const int NT = K >> 6;                      // K-tiles of 64

  const int lane_tail = ((l >> 4) >> 1) * 256 + (l & 15) * 16 + ((l >> 4) & 1) * 8;
  const int a_off = wr * 4096 + lane_tail;            // + mf*1024 + kk*512
  const int b_off = 16384 + wc * 4096 + lane_tail;    // + nf*1024 + kk*512

  f32x4 acc[4][4];
  #pragma unroll
  for (int i = 0; i < 4; i++)
    #pragma unroll
    for (int j = 0; j < 4; j++) acc[i][j] = (f32x4){0.f, 0.f, 0.f, 0.f};

  const int ru = ((tid >> 6) << 4) | (tid & 15);   // rows 0..127 pattern
  const int su = (tid >> 4) & 3;
  const unsigned char* Af0 = A + (size_t)(m0 + ru) * K + su * 16;
  const unsigned char* Bf0 = Bt + (size_t)(n0 + ru) * K + su * 16;
  const size_t rs128 = (size_t)128 * K;

  auto stageA = [&](int kt) {
    int ktw = kt; if (ktw >= NT) ktw -= NT;
    const int k0 = ktw << 6;
    const int bo = (kt & 1) * 24576;
    __builtin_amdgcn_global_load_lds(GPTR(Af0 + k0), LPTR(&lds8[bo + tid * 16]), 16, 0, 0);
    __builtin_amdgcn_global_load_lds(GPTR(Af0 + rs128 + k0), LPTR(&lds8[bo + (tid + 512) * 16]), 16, 0, 0);
  };
  auto stageB = [&](int kt) {
    int ktw = kt; if (ktw >= NT) ktw -= NT;
    const int k0 = ktw << 6;
    const int bo = (kt & 1) * 24576 + 16384;
    __builtin_amdgcn_global_load_lds(GPTR(Bf0 + k0), LPTR(&lds8[bo + tid * 16]), 16, 0, 0);
  };

  stageA(0); stageB(0);   // 3 outstanding

  for (int t = 0; t < NT; t++) {
    const int tbo = (t & 1) * 24576;
    unsigned long long af[4], bfv[4];

    // top: stage A(t+1) [5 out]; vmcnt(2) drains tile t, leaves A(t+1)
    stageA(t + 1);
    SB();
    asm volatile("s_waitcnt vmcnt(2)" ::: "memory");
    SB();
    __builtin_amdgcn_s_barrier();
    SB();
    // kk0
    #pragma unroll
    for (int nf = 0; nf < 4; nf++)
      bfv[nf] = *(const unsigned long long*)&lds8[tbo + b_off + nf * 1024];
    #pragma unroll
    for (int mf = 0; mf < 4; mf++)
      af[mf] = *(const unsigned long long*)&lds8[tbo + a_off + mf * 1024];
    asm volatile("s_waitcnt lgkmcnt(0)" ::: "memory");
    SB();
    __builtin_amdgcn_s_setprio(1);
    #pragma unroll
    for (int mf = 0; mf < 4; mf++)
      #pragma unroll
      for (int nf = 0; nf < 4; nf++)
        acc[mf][nf] = __builtin_amdgcn_mfma_f32_16x16x32_fp8_fp8(
            (long long)bfv[nf], (long long)af[mf], acc[mf][nf], 0, 0, 0);
    __builtin_amdgcn_s_setprio(0);
    SB();
    stageB(t + 1);
    SB();
    // kk1
    #pragma unroll
    for (int nf = 0; nf < 4; nf++)
      bfv[nf] = *(const unsigned long long*)&lds8[tbo + b_off + nf * 1024 + 512];
    #pragma unroll
    for (int mf = 0; mf < 4; mf++)
      af[mf] = *(const unsigned long long*)&lds8[tbo + a_off + mf * 1024 + 512];
    asm volatile("s_waitcnt lgkmcnt(0)" ::: "memory");
    SB();
    __builtin_amdgcn_s_setprio(1);
    #pragma unroll
    for (int mf = 0; mf < 4; mf++)
      #pragma unroll
      for (int nf = 0; nf < 4; nf++)
        acc[mf][nf] = __builtin_amdgcn_mfma_f32_16x16x32_fp8_fp8(
            (long long)bfv[nf], (long long)af[mf], acc[mf][nf], 0, 0, 0);
    __builtin_amdgcn_s_setprio(0);
    SB();
    __builtin_amdgcn_s_barrier();
    SB();
  }
  asm volatile("s_waitcnt vmcnt(0)" ::: "memory");

  const int rowl = m0 + wr * 64 + (l & 15);
  const int coll = n0 + wc * 64 + (l >> 4) * 4;
  #pragma unroll
  for (int mf = 0; mf < 4; mf++) {
    const int row = rowl + mf * 16;
    #pragma unroll
    for (int nf = 0; nf < 4; nf++) {
      const int colb = coll + nf * 16;
      const float4 bv = *(const float4*)(bias + colb);
      const size_t idx = (size_t)row * N + colb;
      const float4 rv = *(const float4*)(resid + idx);
      float4 ov;
      ov.x = acc[mf][nf][0] * WO_SCALE_INV + bv.x + rv.x;
      ov.y = acc[mf][nf][1] * WO_SCALE_INV + bv.y + rv.y;
      ov.z = acc[mf][nf][2] * WO_SCALE_INV + bv.z + rv.z;
      ov.w = acc[mf][nf][3] * WO_SCALE_INV + bv.w + rv.w;
      *(float4*)(Cout + idx) = ov;
    }
  }
}

// ---------------------------------------------------------------------------
// Causal depthwise conv (K=3) + SiLU + gate.  Writes u bf16 AND u fp8 (x128).
// ---------------------------------------------------------------------------
__global__ __launch_bounds__(256) void conv_gate_kernel(
    const unsigned short* __restrict__ proj, const float* __restrict__ conv_w,
    const float* __restrict__ conv_b, unsigned short* __restrict__ u,
    unsigned char* __restrict__ u8) {
  const size_t idx = ((size_t)blockIdx.x * 256 + threadIdx.x) * 8;
  const int d = (int)(idx & (INNER - 1));
  const size_t bt = idx >> 11;
  const int t = (int)(bt & (SS - 1));
  const size_t rowbase = bt * (2 * INNER);
  const ushort8 zero = {0, 0, 0, 0, 0, 0, 0, 0};
  ushort8 p0 = *(const ushort8*)(proj + rowbase + d);
  ushort8 p1 = zero, p2 = zero;
  if (t >= 1) p1 = *(const ushort8*)(proj + rowbase - 2 * INNER + d);
  if (t >= 2) p2 = *(const ushort8*)(proj + rowbase - 4 * INNER + d);
  ushort8 g = *(const ushort8*)(proj + rowbase + INNER + d);
  ushort8 res;
  float us[8];
  #pragma unroll
  for (int j = 0; j < 8; j++) {
    const int dj = d + j;
    float sv = conv_b[dj] + conv_w[dj * 3] * b2f(p2[j]) +
               conv_w[dj * 3 + 1] * b2f(p1[j]) + conv_w[dj * 3 + 2] * b2f(p0[j]);
    float uu = sv * sigmoidf_(sv) * sigmoidf_(b2f(g[j]));
    us[j] = uu;
    res[j] = f2b(uu);
  }
  *(ushort8*)(u + idx) = res;
  uint2 pk;
  pk.x = pk_fp8x4(us[0] * U_SCALE, us[1] * U_SCALE, us[2] * U_SCALE, us[3] * U_SCALE);
  pk.y = pk_fp8x4(us[4] * U_SCALE, us[5] * U_SCALE, us[6] * U_SCALE, us[7] * U_SCALE);
  *(uint2*)(u8 + idx) = pk;
}

// ---------------------------------------------------------------------------
// Chunked parallel scan, 3 phases.
// ---------------------------------------------------------------------------
__global__ __launch_bounds__(256) void scan_phase1(
    const unsigned short* __restrict__ a, const unsigned short* __restrict__ b,
    const unsigned short* __restrict__ u,
    float* __restrict__ P, float* __restrict__ S) {
  const int g = blockIdx.x * 256 + threadIdx.x;   // 65536 threads
  const int ch = (g & (INNER / 4 - 1)) * 4;
  const int chunk = (g >> 9) & (NCHK - 1);
  const int bb = g >> 14;
  size_t base = ((size_t)bb * SS + (size_t)chunk * CHUNK) * INNER + ch;
  float st0 = 0.f, st1 = 0.f, st2 = 0.f, st3 = 0.f;
  float p0 = 1.f, p1 = 1.f, p2 = 1.f, p3 = 1.f;
  for (int t = 0; t < CHUNK; t++) {
    const ushort4v av = *(const ushort4v*)(a + base);
    const ushort4v bv = *(const ushort4v*)(b + base);
    const ushort4v uv = *(const ushort4v*)(u + base);
    const float a0 = b2f(av[0]), a1 = b2f(av[1]), a2 = b2f(av[2]), a3 = b2f(av[3]);
    st0 = fmaf(a0, st0, b2f(bv[0]) * b2f(uv[0])); p0 *= a0;
    st1 = fmaf(a1, st1, b2f(bv[1]) * b2f(uv[1])); p1 *= a1;
    st2 = fmaf(a2, st2, b2f(bv[2]) * b2f(uv[2])); p2 *= a2;
    st3 = fmaf(a3, st3, b2f(bv[3]) * b2f(uv[3])); p3 *= a3;
    base += INNER;
  }
  const size_t o = ((size_t)bb * NCHK + chunk) * INNER + ch;
  *(float4*)(P + o) = (float4){p0, p1, p2, p3};
  *(float4*)(S + o) = (float4){st0, st1, st2, st3};
}

__global__ __launch_bounds__(256) void scan_phase2(
    const float* __restrict__ P, const float* __restrict__ S,
    float* __restrict__ Carry) {
  const int g = blockIdx.x * 256 + threadIdx.x;   // 8192 threads
  const int ch = g & (INNER - 1);
  const int bb = g >> 11;
  float carry = 0.f;
  for (int k = 0; k < NCHK; k++) {
    const size_t o = ((size_t)bb * NCHK + k) * INNER + ch;
    Carry[o] = carry;
    carry = fmaf(P[o], carry, S[o]);
  }
}

// Phase 3: redo local scan; y bf16 over u in-place, plus y fp8 (xY_SCALE).
__global__ __launch_bounds__(256) void scan_phase3(
    const unsigned short* __restrict__ a, const unsigned short* __restrict__ b,
    const unsigned short* __restrict__ c, unsigned short* __restrict__ u,
    unsigned char* __restrict__ y8, const float* __restrict__ Carry) {
  const int g = blockIdx.x * 256 + threadIdx.x;   // 65536 threads
  const int ch = (g & (INNER / 4 - 1)) * 4;
  const int chunk = (g >> 9) & (NCHK - 1);
  const int bb = g >> 14;
  size_t base = ((size_t)bb * SS + (size_t)chunk * CHUNK) * INNER + ch;
  const size_t o = ((size_t)bb * NCHK + chunk) * INNER + ch;
  const float4 cv = *(const float4*)(Carry + o);
  float st0 = cv.x, st1 = cv.y, st2 = cv.z, st3 = cv.w;
  for (int t = 0; t < CHUNK; t++) {
    const ushort4v av = *(const ushort4v*)(a + base);
    const ushort4v bv = *(const ushort4v*)(b + base);
    const ushort4v ccv = *(const ushort4v*)(c + base);
    const ushort4v uv = *(const ushort4v*)(u + base);
    const float u0 = b2f(uv[0]), u1 = b2f(uv[1]), u2 = b2f(uv[2]), u3 = b2f(uv[3]);
    st0 = fmaf(b2f(av[0]), st0, b2f(bv[0]) * u0);
    st1 = fmaf(b2f(av[1]), st1, b2f(bv[1]) * u1);
    st2 = fmaf(b2f(av[2]), st2, b2f(bv[2]) * u2);
    st3 = fmaf(b2f(av[3]), st3, b2f(bv[3]) * u3);
    const float y0 = fmaf(b2f(ccv[0]), st0, u0);
    const float y1 = fmaf(b2f(ccv[1]), st1, u1);
    const float y2 = fmaf(b2f(ccv[2]), st2, u2);
    const float y3 = fmaf(b2f(ccv[3]), st3, u3);
    ushort4v yv;
    yv[0] = f2b(y0); yv[1] = f2b(y1); yv[2] = f2b(y2); yv[3] = f2b(y3);
    *(ushort4v*)(u + base) = yv;
    *(unsigned*)(y8 + base) = pk_fp8x4(y0 * Y_SCALE, y1 * Y_SCALE,
                                       y2 * Y_SCALE, y3 * Y_SCALE);
    base += INNER;
  }
}

// ---------------------------------------------------------------------------
extern "C" void kernel_launch(void* const* d_in, const int* in_sizes, int n_in,
                              void* d_out, int out_size, void* d_ws, size_t ws_size,
                              hipStream_t stream) {
  const float* x      = (const float*)d_in[0];
  const float* W_in   = (const float*)d_in[1];
  const float* b_in   = (const float*)d_in[2];
  const float* conv_w = (const float*)d_in[3];
  const float* conv_b = (const float*)d_in[4];
  const float* Wa     = (const float*)d_in[5];
  const float* ba     = (const float*)d_in[6];
  const float* Wb     = (const float*)d_in[7];
  const float* b_b    = (const float*)d_in[8];
  const float* Wc     = (const float*)d_in[9];
  const float* bc     = (const float*)d_in[10];
  const float* Wo     = (const float*)d_in[11];
  const float* bo     = (const float*)d_in[12];
  const float* gamma  = (const float*)d_in[13];
  const float* beta   = (const float*)d_in[14];
  float* out = (float*)d_out;

  const size_t M = (size_t)BB * SS;  // 8192
  char* ws = (char*)d_ws;
  size_t off = 0;
  auto alloc = [&](size_t bytes) {
    char* p = ws + off;
    off += (bytes + 255) & ~(size_t)255;
    return p;
  };
  unsigned char*  Win8   = (unsigned char*)alloc((size_t)4096 * 1024);     // 4 MB
  unsigned char*  Wabc8  = (unsigned char*)alloc((size_t)6144 * 2048);     // 12 MB
  unsigned char*  Wo8    = (unsigned char*)alloc((size_t)1024 * 2048);     // 2 MB
  float*          biasABC = (float*)alloc(6144 * 4);
  unsigned char*  xn8   = (unsigned char*)alloc(M * DM);                   // 8 MB
  unsigned short* uB    = (unsigned short*)alloc(M * INNER * 2);           // 32 MB
  unsigned char*  u8B   = (unsigned char*)alloc(M * INNER);                // 16 MB
  unsigned short* abc   = (unsigned short*)alloc(3 * M * INNER * 2);       // 96 MB
  unsigned short* proj = abc;
  unsigned short* aB = abc;
  unsigned short* bB = abc + M * INNER;
  unsigned short* cB = abc + 2 * M * INNER;
  float* Pbuf  = (float*)alloc((size_t)BB * NCHK * INNER * 4);             // 1 MB
  float* Sbuf  = (float*)alloc((size_t)BB * NCHK * INNER * 4);             // 1 MB
  float* Carry = (float*)alloc((size_t)BB * NCHK * INNER * 4);             // 1 MB

  hipMemcpyAsync(biasABC,        ba,  2048 * 4, hipMemcpyDeviceToDevice, stream);
  hipMemcpyAsync(biasABC + 2048, b_b, 2048 * 4, hipMemcpyDeviceToDevice, stream);
  hipMemcpyAsync(biasABC + 4096, bc,  2048 * 4, hipMemcpyDeviceToDevice, stream);

  const dim3 tb(32, 8);
  transpose_cast_fp8_kernel<<<dim3(128, 32), tb, 0, stream>>>(W_in, Win8, 1024, 4096, WIN_SCALE);
  transpose_cast_fp8_kernel<<<dim3(64, 64), tb, 0, stream>>>(Wa, Wabc8, 2048, 2048, W_SCALE);
  transpose_cast_fp8_kernel<<<dim3(64, 64), tb, 0, stream>>>(Wb, Wabc8 + 2048 * 2048, 2048, 2048, W_SCALE);
  transpose_cast_fp8_kernel<<<dim3(64, 64), tb, 0, stream>>>(Wc, Wabc8 + 2 * 2048 * 2048, 2048, 2048, W_SCALE);
  transpose_cast_fp8_kernel<<<dim3(32, 64), tb, 0, stream>>>(Wo, Wo8, 2048, 1024, WO_SCALE);

  layernorm_kernel<<<M, 256, 0, stream>>>(x, gamma, beta, xn8);

  // proj = xn @ W_in + b_in            [8192 x 4096] FP8, grid 16x32 = 512
  gemm64_fp8<0><<<dim3(512), 512, 0, stream>>>(
      xn8, Win8, b_in, proj, M, 4096, 1024, 16, PROJ_SCALE_INV);

  // u = silu(conv(projected)) * sigmoid(gate)  (bf16 + fp8 copies)
  conv_gate_kernel<<<(M * INNER) / (256 * 8), 256, 0, stream>>>(
      proj, conv_w, conv_b, uB, u8B);

  // a,b,c fused: [8192 x 6144] FP8, grid 24x32 = 768
  gemm64_fp8<2><<<dim3(768), 512, 0, stream>>>(
      u8B, Wabc8, biasABC, abc, M, 6144, 2048, 24, ABC_SCALE_INV);

  // chunked scan (y overwrites u; y fp8 into u8B)
  scan_phase1<<<256, 256, 0, stream>>>(aB, bB, uB, Pbuf, Sbuf);
  scan_phase2<<<32, 256, 0, stream>>>(Pbuf, Sbuf, Carry);
  scan_phase3<<<256, 256, 0, stream>>>(aB, bB, cB, uB, u8B, Carry);

  // out = x + y @ Wo + bo              [8192 x 1024] fp32 FP8-GEMM, grid 256
  gemm_fp8_wo<<<dim3(256), 512, 0, stream>>>(
      u8B, Wo8, bo, out, x, M, 1024, 2048, 8);
}

// Round 13
// 372.052 us; speedup vs baseline: 1.5899x; 1.0983x over previous
//
#include <hip/hip_runtime.h>
#include <hip/hip_bf16.h>
#include <cstdint>
#include <cstddef>

#define BB 4
#define SS 2048
#define DM 1024
#define INNER 2048
#define CHUNK 64
#define NCHK (SS / CHUNK)  // 32

typedef __attribute__((ext_vector_type(8))) __bf16 bf16x8;
typedef __attribute__((ext_vector_type(4))) float f32x4;
typedef __attribute__((ext_vector_type(16))) float f32x16;
typedef __attribute__((ext_vector_type(8))) int i32x8;
typedef __attribute__((ext_vector_type(4))) int i32x4;
typedef __attribute__((ext_vector_type(8))) unsigned short ushort8;
typedef __attribute__((ext_vector_type(4))) unsigned short ushort4v;

#define GPTR(p) ((const __attribute__((address_space(1))) void*)(p))
#define LPTR(p) ((__attribute__((address_space(3))) void*)(p))
#define SB() __builtin_amdgcn_sched_barrier(0)

// Unit E8M0 scales (1.0) -> identical math to non-scaled fp8, 2x MFMA rate.
#define MXMFMA(b, a, c) \
  __builtin_amdgcn_mfma_scale_f32_32x32x64_f8f6f4((b), (a), (c), 0, 0, 0, 0x7f7f7f7f, 0, 0x7f7f7f7f)

// fp8 pre-scales (powers of 2; undone in GEMM epilogues)
#define XN_SCALE 8.0f
#define WIN_SCALE 32.0f
#define PROJ_SCALE_INV (1.0f / 256.0f)
#define U_SCALE 128.0f
#define W_SCALE 32.0f
#define ABC_SCALE_INV (1.0f / 4096.0f)
#define Y_SCALE 128.0f
#define WO_SCALE 32.0f
#define WO_SCALE_INV (1.0f / 4096.0f)

__device__ inline float b2f(unsigned short h) {
  union { unsigned u; float f; } v; v.u = ((unsigned)h) << 16; return v.f;
}
__device__ inline unsigned short f2b(float f) {
  unsigned u = __float_as_uint(f);
  u += 0x7fff + ((u >> 16) & 1);   // round-to-nearest-even
  return (unsigned short)(u >> 16);
}
__device__ inline unsigned pack2(float lo, float hi) {
  return (unsigned)f2b(lo) | ((unsigned)f2b(hi) << 16);
}
__device__ inline unsigned pk_fp8x4(float a, float b, float c, float d) {
  unsigned w = 0;
  w = __builtin_amdgcn_cvt_pk_fp8_f32(a, b, (int)w, 0);
  w = __builtin_amdgcn_cvt_pk_fp8_f32(c, d, (int)w, 1);
  return w;
}
__device__ inline float sigmoidf_(float x) { return 1.0f / (1.0f + __expf(-x)); }
__device__ inline float tanhf_(float x) { return 2.0f / (1.0f + __expf(-2.0f * x)) - 1.0f; }

// 32-byte MX fragment: two b128 reads at +0 / +256 (k-halves), regs linear in k
__device__ inline i32x8 ld32(const unsigned char* p) {
  i32x4 lo = *(const i32x4*)p;
  i32x4 hi = *(const i32x4*)(p + 256);
  i32x8 r;
  r[0] = lo[0]; r[1] = lo[1]; r[2] = lo[2]; r[3] = lo[3];
  r[4] = hi[0]; r[5] = hi[1]; r[6] = hi[2]; r[7] = hi[3];
  return r;
}

// ---------------------------------------------------------------------------
// Transpose + cast to fp8 e4m3 (scaled): src fp32 [R][C] -> dst fp8 [C][R]
// ---------------------------------------------------------------------------
__global__ void transpose_cast_fp8_kernel(const float* __restrict__ src,
                                          unsigned char* __restrict__ dst,
                                          int R, int C, float scale) {
  __shared__ float tile[32][33];
  const int c0 = blockIdx.x * 32, r0 = blockIdx.y * 32;
  const int tx = threadIdx.x, ty = threadIdx.y;  // (32,8)
  #pragma unroll
  for (int j = ty; j < 32; j += 8)
    tile[j][tx] = src[(size_t)(r0 + j) * C + c0 + tx];
  __syncthreads();
  #pragma unroll
  for (int j = ty; j < 32; j += 8) {
    const int w = __builtin_amdgcn_cvt_pk_fp8_f32(tile[tx][j] * scale, 0.f, 0, 0);
    dst[(size_t)(c0 + j) * R + r0 + tx] = (unsigned char)(w & 0xff);
  }
}

// ---------------------------------------------------------------------------
// LayerNorm: x fp32 [8192][1024] -> xn fp8 e4m3 (x XN_SCALE)
// ---------------------------------------------------------------------------
__global__ __launch_bounds__(256) void layernorm_kernel(
    const float* __restrict__ x, const float* __restrict__ gamma,
    const float* __restrict__ beta, unsigned char* __restrict__ out) {
  const int row = blockIdx.x;
  const int tid = threadIdx.x;
  const float4 v = *(const float4*)(x + (size_t)row * DM + tid * 4);
  float s = v.x + v.y + v.z + v.w;
  #pragma unroll
  for (int o = 32; o >= 1; o >>= 1) s += __shfl_down(s, o, 64);
  __shared__ float red[8];
  const int wid = tid >> 6, lane = tid & 63;
  if (lane == 0) red[wid] = s;
  __syncthreads();
  const float mu = (red[0] + red[1] + red[2] + red[3]) * (1.f / DM);
  const float d0 = v.x - mu, d1 = v.y - mu, d2 = v.z - mu, d3 = v.w - mu;
  float sq = d0 * d0 + d1 * d1 + d2 * d2 + d3 * d3;
  #pragma unroll
  for (int o = 32; o >= 1; o >>= 1) sq += __shfl_down(sq, o, 64);
  if (lane == 0) red[4 + wid] = sq;
  __syncthreads();
  const float var = (red[4] + red[5] + red[6] + red[7]) * (1.f / DM);
  const float rs = rsqrtf(var + 1e-5f);
  const int c0 = tid * 4;
  const float o0 = (d0 * rs * gamma[c0 + 0] + beta[c0 + 0]) * XN_SCALE;
  const float o1 = (d1 * rs * gamma[c0 + 1] + beta[c0 + 1]) * XN_SCALE;
  const float o2 = (d2 * rs * gamma[c0 + 2] + beta[c0 + 2]) * XN_SCALE;
  const float o3 = (d3 * rs * gamma[c0 + 3] + beta[c0 + 3]) * XN_SCALE;
  *(unsigned*)(out + (size_t)row * DM + c0) = pk_fp8x4(o0, o1, o2, o3);
}

// ---------------------------------------------------------------------------
// MX-fp8 256x256 GEMM, BK=64, 512 threads (8 waves 2Mx4N, wave tile 128x64).
// 32x32x64 scaled MFMA (unit scales) -> 8 MFMAs/wave/K-tile, acc f32x16[4][2].
// LDS layout + staging + vmcnt ledger IDENTICAL to the R10-verified fp8 kernel:
//   region addr(r, s16) = (r>>4)*1024 + s*256 + (r&15)*16; A @0, B @16384.
// A-frag: lane row = l&31 (+mf*32+wr*128), k-window (l>>5)*32 -> 2 b128 at
//   +0/+256, lane-linear per 16-lane group: conflict-free.
// Swapped operands: mfma(B, A, acc) -> lane holds C-row l&31, col clusters
//   4*(l>>5) + 8g + {0..3} (C/D 32x32 layout, dtype-independent).
// OUTMODE 0: bf16 (v = acc*sinv + bias). OUTMODE 2: abc-fused.
// ---------------------------------------------------------------------------
template <int OUTMODE>
__global__ __launch_bounds__(512, 1) void gemm_mx(
    const unsigned char* __restrict__ A, const unsigned char* __restrict__ Bt,
    const float* __restrict__ bias, unsigned short* __restrict__ Cout,
    int M, int N, int K, int nbx, float sinv) {
  __shared__ __align__(16) unsigned char lds8[2 * 32768];  // 64 KB
  const int tid = threadIdx.x;
  const int nwg = gridDim.x;
  const int cpx = nwg >> 3;
  const int bid = blockIdx.x;
  const int swz = (bid & 7) * cpx + (bid >> 3);
  const int m0 = (swz / nbx) * 256, n0 = (swz % nbx) * 256;

  const int l = tid & 63, w = tid >> 6;
  const int wr = w >> 2, wc = w & 3;          // 2(M) x 4(N)
  const int NT = K >> 6;                      // K-tiles of 64

  const int lane_a = ((l >> 4) & 1) * 1024 + (l >> 5) * 512 + (l & 15) * 16;
  const int a_base = wr * 8192 + lane_a;              // + mf*2048
  const int b_base = 16384 + wc * 4096 + lane_a;      // + nf*2048

  f32x16 acc[4][2];
  {
    f32x16 z;
    #pragma unroll
    for (int e = 0; e < 16; e++) z[e] = 0.f;
    #pragma unroll
    for (int i = 0; i < 4; i++)
      #pragma unroll
      for (int j = 0; j < 2; j++) acc[i][j] = z;
  }

  const int ru = ((tid >> 6) << 4) | (tid & 15);
  const int su = (tid >> 4) & 3;
  const unsigned char* Af0 = A + (size_t)(m0 + ru) * K + su * 16;
  const unsigned char* Bf0 = Bt + (size_t)(n0 + ru) * K + su * 16;
  const size_t rs128 = (size_t)128 * K;

  auto stageA = [&](int kt) {
    int ktw = kt; if (ktw >= NT) ktw -= NT;
    const int k0 = ktw << 6;
    const int bo = (kt & 1) * 32768;
    __builtin_amdgcn_global_load_lds(GPTR(Af0 + k0), LPTR(&lds8[bo + tid * 16]), 16, 0, 0);
    __builtin_amdgcn_global_load_lds(GPTR(Af0 + rs128 + k0), LPTR(&lds8[bo + (tid + 512) * 16]), 16, 0, 0);
  };
  auto stageB = [&](int kt) {
    int ktw = kt; if (ktw >= NT) ktw -= NT;
    const int k0 = ktw << 6;
    const int bo = (kt & 1) * 32768 + 16384;
    __builtin_amdgcn_global_load_lds(GPTR(Bf0 + k0), LPTR(&lds8[bo + tid * 16]), 16, 0, 0);
    __builtin_amdgcn_global_load_lds(GPTR(Bf0 + rs128 + k0), LPTR(&lds8[bo + (tid + 512) * 16]), 16, 0, 0);
  };

  stageA(0); stageB(0);   // 4 outstanding

  for (int t = 0; t < NT; t++) {
    const int tbo = (t & 1) * 32768;
    i32x8 bf0, bf1, af0, af1, af2, af3;

    // boundary: stage A(t+1) [6 out]; vmcnt(2) -> tile t resident
    stageA(t + 1);
    SB();
    asm volatile("s_waitcnt vmcnt(2)" ::: "memory");
    SB();
    __builtin_amdgcn_s_barrier();
    SB();
    bf0 = ld32(&lds8[tbo + b_base]);
    bf1 = ld32(&lds8[tbo + b_base + 2048]);
    af0 = ld32(&lds8[tbo + a_base]);
    af1 = ld32(&lds8[tbo + a_base + 2048]);
    SB();
    __builtin_amdgcn_s_setprio(1);
    acc[0][0] = MXMFMA(bf0, af0, acc[0][0]);
    acc[0][1] = MXMFMA(bf1, af0, acc[0][1]);
    acc[1][0] = MXMFMA(bf0, af1, acc[1][0]);
    acc[1][1] = MXMFMA(bf1, af1, acc[1][1]);
    __builtin_amdgcn_s_setprio(0);
    SB();
    stageB(t + 1);
    SB();
    af2 = ld32(&lds8[tbo + a_base + 2 * 2048]);
    af3 = ld32(&lds8[tbo + a_base + 3 * 2048]);
    SB();
    __builtin_amdgcn_s_setprio(1);
    acc[2][0] = MXMFMA(bf0, af2, acc[2][0]);
    acc[2][1] = MXMFMA(bf1, af2, acc[2][1]);
    acc[3][0] = MXMFMA(bf0, af3, acc[3][0]);
    acc[3][1] = MXMFMA(bf1, af3, acc[3][1]);
    __builtin_amdgcn_s_setprio(0);
    SB();
    __builtin_amdgcn_s_barrier();
    SB();
  }
  asm volatile("s_waitcnt vmcnt(0)" ::: "memory");

  // epilogue: lane holds C-row l&31, col clusters 4*(l>>5)+8g+{0..3}
  const int rowl = m0 + wr * 128 + (l & 31);
  const int colg = 4 * (l >> 5);
  const int seg = (OUTMODE == 2) ? (n0 >> 11) : 0;
  unsigned short* outseg = Cout + (OUTMODE == 2 ? (size_t)seg * M * 2048 : 0);
  #pragma unroll
  for (int mf = 0; mf < 4; mf++) {
    const int row = rowl + mf * 32;
    #pragma unroll
    for (int nf = 0; nf < 2; nf++) {
      const int nb = n0 + wc * 64 + nf * 32 + colg;
      #pragma unroll
      for (int g = 0; g < 4; g++) {
        const int col = nb + g * 8;
        const float4 bv = *(const float4*)(bias + col);
        float v0 = acc[mf][nf][g * 4 + 0] * sinv + bv.x;
        float v1 = acc[mf][nf][g * 4 + 1] * sinv + bv.y;
        float v2 = acc[mf][nf][g * 4 + 2] * sinv + bv.z;
        float v3 = acc[mf][nf][g * 4 + 3] * sinv + bv.w;
        if (OUTMODE == 2) {
          if (seg == 2) {
            v0 = tanhf_(v0); v1 = tanhf_(v1); v2 = tanhf_(v2); v3 = tanhf_(v3);
          } else {
            v0 = sigmoidf_(v0); v1 = sigmoidf_(v1); v2 = sigmoidf_(v2); v3 = sigmoidf_(v3);
          }
          uint2 pk = {pack2(v0, v1), pack2(v2, v3)};
          *(uint2*)(outseg + (size_t)row * 2048 + (col & 2047)) = pk;
        } else {
          uint2 pk = {pack2(v0, v1), pack2(v2, v3)};
          *(uint2*)(Cout + (size_t)row * N + col) = pk;
        }
      }
    }
  }
}

// ---------------------------------------------------------------------------
// MX-fp8 256x128 GEMM for Wo. 8 waves 4Mx2N, wave tile 64x64 -> 4 MFMAs,
// acc f32x16[2][2]. Same LDS/staging/ledger as R11 Wo kernel.
// Epilogue: fp32 out = acc*WO_SCALE_INV + bias + resid (float4).
// ---------------------------------------------------------------------------
__global__ __launch_bounds__(512, 1) void gemm_mx_wo(
    const unsigned char* __restrict__ A, const unsigned char* __restrict__ Bt,
    const float* __restrict__ bias, float* __restrict__ Cout,
    const float* __restrict__ resid, int M, int N, int K, int nbx) {
  __shared__ __align__(16) unsigned char lds8[2 * 24576];  // 48 KB
  const int tid = threadIdx.x;
  const int nwg = gridDim.x;
  const int cpx = nwg >> 3;
  const int bid = blockIdx.x;
  const int swz = (bid & 7) * cpx + (bid >> 3);
  const int m0 = (swz / nbx) * 256, n0 = (swz % nbx) * 128;

  const int l = tid & 63, w = tid >> 6;
  const int wr = w >> 1, wc = w & 1;          // 4(M) x 2(N)
  const int NT = K >> 6;

  const int lane_a = ((l >> 4) & 1) * 1024 + (l >> 5) * 512 + (l & 15) * 16;
  const int a_base = wr * 4096 + lane_a;              // + mf*2048
  const int b_base = 16384 + wc * 4096 + lane_a;      // + nf*2048

  f32x16 acc[2][2];
  {
    f32x16 z;
    #pragma unroll
    for (int e = 0; e < 16; e++) z[e] = 0.f;
    acc[0][0] = z; acc[0][1] = z; acc[1][0] = z; acc[1][1] = z;
  }

  const int ru = ((tid >> 6) << 4) | (tid & 15);
  const int su = (tid >> 4) & 3;
  const unsigned char* Af0 = A + (size_t)(m0 + ru) * K + su * 16;
  const unsigned char* Bf0 = Bt + (size_t)(n0 + ru) * K + su * 16;
  const size_t rs128 = (size_t)128 * K;

  auto stageA = [&](int kt) {
    int ktw = kt; if (ktw >= NT) ktw -= NT;
    const int k0 = ktw << 6;
    const int bo = (kt & 1) * 24576;
    __builtin_amdgcn_global_load_lds(GPTR(Af0 + k0), LPTR(&lds8[bo + tid * 16]), 16, 0, 0);
    __builtin_amdgcn_global_load_lds(GPTR(Af0 + rs128 + k0), LPTR(&lds8[bo + (tid + 512) * 16]), 16, 0, 0);
  };
  auto stageB = [&](int kt) {
    int ktw = kt; if (ktw >= NT) ktw -= NT;
    const int k0 = ktw << 6;
    const int bo = (kt & 1) * 24576 + 16384;
    __builtin_amdgcn_global_load_lds(GPTR(Bf0 + k0), LPTR(&lds8[bo + tid * 16]), 16, 0, 0);
  };

  stageA(0); stageB(0);   // 3 outstanding

  for (int t = 0; t < NT; t++) {
    const int tbo = (t & 1) * 24576;
    i32x8 bf0, bf1, af0, af1;

    stageA(t + 1);
    SB();
    asm volatile("s_waitcnt vmcnt(2)" ::: "memory");
    SB();
    __builtin_amdgcn_s_barrier();
    SB();
    bf0 = ld32(&lds8[tbo + b_base]);
    bf1 = ld32(&lds8[tbo + b_base + 2048]);
    af0 = ld32(&lds8[tbo + a_base]);
    SB();
    __builtin_amdgcn_s_setprio(1);
    acc[0][0] = MXMFMA(bf0, af0, acc[0][0]);
    acc[0][1] = MXMFMA(bf1, af0, acc[0][1]);
    __builtin_amdgcn_s_setprio(0);
    SB();
    stageB(t + 1);
    SB();
    af1 = ld32(&lds8[tbo + a_base + 2048]);
    SB();
    __builtin_amdgcn_s_setprio(1);
    acc[1][0] = MXMFMA(bf0, af1, acc[1][0]);
    acc[1][1] = MXMFMA(bf1, af1, acc[1][1]);
    __builtin_amdgcn_s_setprio(0);
    SB();
    __builtin_amdgcn_s_barrier();
    SB();
  }
  asm volatile("s_waitcnt vmcnt(0)" ::: "memory");

  const int rowl = m0 + wr * 64 + (l & 31);
  const int colg = 4 * (l >> 5);
  #pragma unroll
  for (int mf = 0; mf < 2; mf++) {
    const int row = rowl + mf * 32;
    #pragma unroll
    for (int nf = 0; nf < 2; nf++) {
      const int nb = n0 + wc * 64 + nf * 32 + colg;
      #pragma unroll
      for (int g = 0; g < 4; g++) {
        const int col = nb + g * 8;
        const float4 bv = *(const float4*)(bias + col);
        const size_t idx = (size_t)row * N + col;
        const float4 rv = *(const float4*)(resid + idx);
        float4 ov;
        ov.x = acc[mf][nf][g * 4 + 0] * WO_SCALE_INV + bv.x + rv.x;
        ov.y = acc[mf][nf][g * 4 + 1] * WO_SCALE_INV + bv.y + rv.y;
        ov.z = acc[mf][nf][g * 4 + 2] * WO_SCALE_INV + bv.z + rv.z;
        ov.w = acc[mf][nf][g * 4 + 3] * WO_SCALE_INV + bv.w + rv.w;
        *(float4*)(Cout + idx) = ov;
      }
    }
  }
}

// ---------------------------------------------------------------------------
// Causal depthwise conv (K=3) + SiLU + gate.  Writes u bf16 AND u fp8 (x128).
// ---------------------------------------------------------------------------
__global__ __launch_bounds__(256) void conv_gate_kernel(
    const unsigned short* __restrict__ proj, const float* __restrict__ conv_w,
    const float* __restrict__ conv_b, unsigned short* __restrict__ u,
    unsigned char* __restrict__ u8) {
  const size_t idx = ((size_t)blockIdx.x * 256 + threadIdx.x) * 8;
  const int d = (int)(idx & (INNER - 1));
  const size_t bt = idx >> 11;
  const int t = (int)(bt & (SS - 1));
  const size_t rowbase = bt * (2 * INNER);
  const ushort8 zero = {0, 0, 0, 0, 0, 0, 0, 0};
  ushort8 p0 = *(const ushort8*)(proj + rowbase + d);
  ushort8 p1 = zero, p2 = zero;
  if (t >= 1) p1 = *(const ushort8*)(proj + rowbase - 2 * INNER + d);
  if (t >= 2) p2 = *(const ushort8*)(proj + rowbase - 4 * INNER + d);
  ushort8 g = *(const ushort8*)(proj + rowbase + INNER + d);
  ushort8 res;
  float us[8];
  #pragma unroll
  for (int j = 0; j < 8; j++) {
    const int dj = d + j;
    float sv = conv_b[dj] + conv_w[dj * 3] * b2f(p2[j]) +
               conv_w[dj * 3 + 1] * b2f(p1[j]) + conv_w[dj * 3 + 2] * b2f(p0[j]);
    float uu = sv * sigmoidf_(sv) * sigmoidf_(b2f(g[j]));
    us[j] = uu;
    res[j] = f2b(uu);
  }
  *(ushort8*)(u + idx) = res;
  uint2 pk;
  pk.x = pk_fp8x4(us[0] * U_SCALE, us[1] * U_SCALE, us[2] * U_SCALE, us[3] * U_SCALE);
  pk.y = pk_fp8x4(us[4] * U_SCALE, us[5] * U_SCALE, us[6] * U_SCALE, us[7] * U_SCALE);
  *(uint2*)(u8 + idx) = pk;
}

// ---------------------------------------------------------------------------
// Chunked parallel scan, 3 phases.
// ---------------------------------------------------------------------------
__global__ __launch_bounds__(256) void scan_phase1(
    const unsigned short* __restrict__ a, const unsigned short* __restrict__ b,
    const unsigned short* __restrict__ u,
    float* __restrict__ P, float* __restrict__ S) {
  const int g = blockIdx.x * 256 + threadIdx.x;   // 65536 threads
  const int ch = (g & (INNER / 4 - 1)) * 4;
  const int chunk = (g >> 9) & (NCHK - 1);
  const int bb = g >> 14;
  size_t base = ((size_t)bb * SS + (size_t)chunk * CHUNK) * INNER + ch;
  float st0 = 0.f, st1 = 0.f, st2 = 0.f, st3 = 0.f;
  float p0 = 1.f, p1 = 1.f, p2 = 1.f, p3 = 1.f;
  for (int t = 0; t < CHUNK; t++) {
    const ushort4v av = *(const ushort4v*)(a + base);
    const ushort4v bv = *(const ushort4v*)(b + base);
    const ushort4v uv = *(const ushort4v*)(u + base);
    const float a0 = b2f(av[0]), a1 = b2f(av[1]), a2 = b2f(av[2]), a3 = b2f(av[3]);
    st0 = fmaf(a0, st0, b2f(bv[0]) * b2f(uv[0])); p0 *= a0;
    st1 = fmaf(a1, st1, b2f(bv[1]) * b2f(uv[1])); p1 *= a1;
    st2 = fmaf(a2, st2, b2f(bv[2]) * b2f(uv[2])); p2 *= a2;
    st3 = fmaf(a3, st3, b2f(bv[3]) * b2f(uv[3])); p3 *= a3;
    base += INNER;
  }
  const size_t o = ((size_t)bb * NCHK + chunk) * INNER + ch;
  *(float4*)(P + o) = (float4){p0, p1, p2, p3};
  *(float4*)(S + o) = (float4){st0, st1, st2, st3};
}

__global__ __launch_bounds__(256) void scan_phase2(
    const float* __restrict__ P, const float* __restrict__ S,
    float* __restrict__ Carry) {
  const int g = blockIdx.x * 256 + threadIdx.x;   // 8192 threads
  const int ch = g & (INNER - 1);
  const int bb = g >> 11;
  float carry = 0.f;
  for (int k = 0; k < NCHK; k++) {
    const size_t o = ((size_t)bb * NCHK + k) * INNER + ch;
    Carry[o] = carry;
    carry = fmaf(P[o], carry, S[o]);
  }
}

// Phase 3: redo local scan; y bf16 over u in-place, plus y fp8 (xY_SCALE).
__global__ __launch_bounds__(256) void scan_phase3(
    const unsigned short* __restrict__ a, const unsigned short* __restrict__ b,
    const unsigned short* __restrict__ c, unsigned short* __restrict__ u,
    unsigned char* __restrict__ y8, const float* __restrict__ Carry) {
  const int g = blockIdx.x * 256 + threadIdx.x;   // 65536 threads
  const int ch = (g & (INNER / 4 - 1)) * 4;
  const int chunk = (g >> 9) & (NCHK - 1);
  const int bb = g >> 14;
  size_t base = ((size_t)bb * SS + (size_t)chunk * CHUNK) * INNER + ch;
  const size_t o = ((size_t)bb * NCHK + chunk) * INNER + ch;
  const float4 cv = *(const float4*)(Carry + o);
  float st0 = cv.x, st1 = cv.y, st2 = cv.z, st3 = cv.w;
  for (int t = 0; t < CHUNK; t++) {
    const ushort4v av = *(const ushort4v*)(a + base);
    const ushort4v bv = *(const ushort4v*)(b + base);
    const ushort4v ccv = *(const ushort4v*)(c + base);
    const ushort4v uv = *(const ushort4v*)(u + base);
    const float u0 = b2f(uv[0]), u1 = b2f(uv[1]), u2 = b2f(uv[2]), u3 = b2f(uv[3]);
    st0 = fmaf(b2f(av[0]), st0, b2f(bv[0]) * u0);
    st1 = fmaf(b2f(av[1]), st1, b2f(bv[1]) * u1);
    st2 = fmaf(b2f(av[2]), st2, b2f(bv[2]) * u2);
    st3 = fmaf(b2f(av[3]), st3, b2f(bv[3]) * u3);
    const float y0 = fmaf(b2f(ccv[0]), st0, u0);
    const float y1 = fmaf(b2f(ccv[1]), st1, u1);
    const float y2 = fmaf(b2f(ccv[2]), st2, u2);
    const float y3 = fmaf(b2f(ccv[3]), st3, u3);
    ushort4v yv;
    yv[0] = f2b(y0); yv[1] = f2b(y1); yv[2] = f2b(y2); yv[3] = f2b(y3);
    *(ushort4v*)(u + base) = yv;
    *(unsigned*)(y8 + base) = pk_fp8x4(y0 * Y_SCALE, y1 * Y_SCALE,
                                       y2 * Y_SCALE, y3 * Y_SCALE);
    base += INNER;
  }
}

// ---------------------------------------------------------------------------
extern "C" void kernel_launch(void* const* d_in, const int* in_sizes, int n_in,
                              void* d_out, int out_size, void* d_ws, size_t ws_size,
                              hipStream_t stream) {
  const float* x      = (const float*)d_in[0];
  const float* W_in   = (const float*)d_in[1];
  const float* b_in   = (const float*)d_in[2];
  const float* conv_w = (const float*)d_in[3];
  const float* conv_b = (const float*)d_in[4];
  const float* Wa     = (const float*)d_in[5];
  const float* ba     = (const float*)d_in[6];
  const float* Wb     = (const float*)d_in[7];
  const float* b_b    = (const float*)d_in[8];
  const float* Wc     = (const float*)d_in[9];
  const float* bc     = (const float*)d_in[10];
  const float* Wo     = (const float*)d_in[11];
  const float* bo     = (const float*)d_in[12];
  const float* gamma  = (const float*)d_in[13];
  const float* beta   = (const float*)d_in[14];
  float* out = (float*)d_out;

  const size_t M = (size_t)BB * SS;  // 8192
  char* ws = (char*)d_ws;
  size_t off = 0;
  auto alloc = [&](size_t bytes) {
    char* p = ws + off;
    off += (bytes + 255) & ~(size_t)255;
    return p;
  };
  unsigned char*  Win8   = (unsigned char*)alloc((size_t)4096 * 1024);     // 4 MB
  unsigned char*  Wabc8  = (unsigned char*)alloc((size_t)6144 * 2048);     // 12 MB
  unsigned char*  Wo8    = (unsigned char*)alloc((size_t)1024 * 2048);     // 2 MB
  float*          biasABC = (float*)alloc(6144 * 4);
  unsigned char*  xn8   = (unsigned char*)alloc(M * DM);                   // 8 MB
  unsigned short* uB    = (unsigned short*)alloc(M * INNER * 2);           // 32 MB
  unsigned char*  u8B   = (unsigned char*)alloc(M * INNER);                // 16 MB
  unsigned short* abc   = (unsigned short*)alloc(3 * M * INNER * 2);       // 96 MB
  unsigned short* proj = abc;
  unsigned short* aB = abc;
  unsigned short* bB = abc + M * INNER;
  unsigned short* cB = abc + 2 * M * INNER;
  float* Pbuf  = (float*)alloc((size_t)BB * NCHK * INNER * 4);             // 1 MB
  float* Sbuf  = (float*)alloc((size_t)BB * NCHK * INNER * 4);             // 1 MB
  float* Carry = (float*)alloc((size_t)BB * NCHK * INNER * 4);             // 1 MB

  hipMemcpyAsync(biasABC,        ba,  2048 * 4, hipMemcpyDeviceToDevice, stream);
  hipMemcpyAsync(biasABC + 2048, b_b, 2048 * 4, hipMemcpyDeviceToDevice, stream);
  hipMemcpyAsync(biasABC + 4096, bc,  2048 * 4, hipMemcpyDeviceToDevice, stream);

  const dim3 tb(32, 8);
  transpose_cast_fp8_kernel<<<dim3(128, 32), tb, 0, stream>>>(W_in, Win8, 1024, 4096, WIN_SCALE);
  transpose_cast_fp8_kernel<<<dim3(64, 64), tb, 0, stream>>>(Wa, Wabc8, 2048, 2048, W_SCALE);
  transpose_cast_fp8_kernel<<<dim3(64, 64), tb, 0, stream>>>(Wb, Wabc8 + 2048 * 2048, 2048, 2048, W_SCALE);
  transpose_cast_fp8_kernel<<<dim3(64, 64), tb, 0, stream>>>(Wc, Wabc8 + 2 * 2048 * 2048, 2048, 2048, W_SCALE);
  transpose_cast_fp8_kernel<<<dim3(32, 64), tb, 0, stream>>>(Wo, Wo8, 2048, 1024, WO_SCALE);

  layernorm_kernel<<<M, 256, 0, stream>>>(x, gamma, beta, xn8);

  // proj = xn @ W_in + b_in            [8192 x 4096] MX-fp8, grid 16x32 = 512
  gemm_mx<0><<<dim3(512), 512, 0, stream>>>(
      xn8, Win8, b_in, proj, M, 4096, 1024, 16, PROJ_SCALE_INV);

  // u = silu(conv(projected)) * sigmoid(gate)  (bf16 + fp8 copies)
  conv_gate_kernel<<<(M * INNER) / (256 * 8), 256, 0, stream>>>(
      proj, conv_w, conv_b, uB, u8B);

  // a,b,c fused: [8192 x 6144] MX-fp8, grid 24x32 = 768
  gemm_mx<2><<<dim3(768), 512, 0, stream>>>(
      u8B, Wabc8, biasABC, abc, M, 6144, 2048, 24, ABC_SCALE_INV);

  // chunked scan (y overwrites u; y fp8 into u8B)
  scan_phase1<<<256, 256, 0, stream>>>(aB, bB, uB, Pbuf, Sbuf);
  scan_phase2<<<32, 256, 0, stream>>>(Pbuf, Sbuf, Carry);
  scan_phase3<<<256, 256, 0, stream>>>(aB, bB, cB, uB, u8B, Carry);

  // out = x + y @ Wo + bo              [8192 x 1024] fp32 MX-fp8, grid 256
  gemm_mx_wo<<<dim3(256), 512, 0, stream>>>(
      u8B, Wo8, bo, out, x, M, 1024, 2048, 8);
}